// Round 2
// baseline (14159.868 us; speedup 1.0000x reference)
//
#include <hip/hip_runtime.h>
#include <hip/hip_bf16.h>
#include <math.h>

// Problem constants
#define BB 4
#define LL 2048
#define DD 512
#define HH 8
#define NLAYER 4
#define VV 258
#define WW 8
#define HDIM 64
#define MM (BB * LL)   // 8192 rows

// ---------------------------------------------------------------------------
// Kernel 1: token embedding + sliding-window byte-entropy feature
// h[b,l,d] = emb[x[b,l], d] + ent(b,l) * ent_w[d] + ent_b[d]
// ent over window x[b, l:l+8] for l <= L-W; values >= 256 contribute nothing
// (reference one_hot has 256 classes while V=258).
// ---------------------------------------------------------------------------
__global__ __launch_bounds__(256)
void embed_ent_kernel(const int* __restrict__ x,
                      const float* __restrict__ emb,
                      const float* __restrict__ ent_w,
                      const float* __restrict__ ent_b,
                      float* __restrict__ h)
{
    int row = blockIdx.x;            // 0..MM-1
    int b = row / LL, l = row % LL;

    float ent = 0.f;
    if (l <= LL - WW) {
        int win[WW];
        #pragma unroll
        for (int i = 0; i < WW; i++) win[i] = x[b * LL + l + i];
        float s = 0.f;
        #pragma unroll
        for (int i = 0; i < WW; i++) {
            if (win[i] < 256) {
                int c = 0;
                #pragma unroll
                for (int j = 0; j < WW; j++) c += (win[j] == win[i]) ? 1 : 0;
                // p*log2(p+1e-10) accumulated per occurrence
                s += log2f((float)c * 0.125f + 1e-10f);
            }
        }
        ent = -s * 0.125f;
    }

    int tok = x[b * LL + l];
    const float* erow = emb + (size_t)tok * DD;
    float* hrow = h + (size_t)row * DD;
    for (int d = threadIdx.x; d < DD; d += blockDim.x) {
        hrow[d] = erow[d] + ent * ent_w[d] + ent_b[d];
    }
}

// ---------------------------------------------------------------------------
// Kernel 2: LayerNorm  g = (h - mu) * rsqrt(var + 1e-5) * scale + bias
// one block (256 threads) per row of D=512
// ---------------------------------------------------------------------------
__global__ __launch_bounds__(256)
void ln_kernel(const float* __restrict__ h,
               const float* __restrict__ scale,
               const float* __restrict__ bias,
               float* __restrict__ g)
{
    int row = blockIdx.x;
    const float* hr = h + (size_t)row * DD;
    float* gr = g + (size_t)row * DD;

    float sum = 0.f, sumsq = 0.f;
    for (int d = threadIdx.x; d < DD; d += 256) {
        float v = hr[d];
        sum += v; sumsq += v * v;
    }
    #pragma unroll
    for (int off = 32; off > 0; off >>= 1) {
        sum   += __shfl_down(sum, off);
        sumsq += __shfl_down(sumsq, off);
    }
    __shared__ float red0[4], red1[4];
    int wid = threadIdx.x >> 6, lane = threadIdx.x & 63;
    if (lane == 0) { red0[wid] = sum; red1[wid] = sumsq; }
    __syncthreads();
    if (threadIdx.x == 0) {
        float a = 0.f, q = 0.f;
        #pragma unroll
        for (int i = 0; i < 4; i++) { a += red0[i]; q += red1[i]; }
        red0[0] = a; red1[0] = q;
    }
    __syncthreads();
    float mu = red0[0] * (1.f / DD);
    float var = red1[0] * (1.f / DD) - mu * mu;
    float rstd = rsqrtf(var + 1e-5f);

    for (int d = threadIdx.x; d < DD; d += 256) {
        gr[d] = (hr[d] - mu) * rstd * scale[d] + bias[d];
    }
}

// ---------------------------------------------------------------------------
// Kernel 3: GEMM  C[M,N] = A[M,K] * Bw[N,K]^T  (+bias)(+gelu)(+resid)
// 64x64 tile, 16 K-step, 256 threads, 4x4 per thread. M % 64 == 0.
// ---------------------------------------------------------------------------
template<bool HAS_BIAS, bool GELU, bool RESID>
__global__ __launch_bounds__(256)
void gemm_nt(const float* __restrict__ A,
             const float* __restrict__ Bw,
             const float* __restrict__ bias,
             const float* __restrict__ resid,
             float* __restrict__ C,
             int Nn, int Kk)
{
    __shared__ float As[16][65];
    __shared__ float Bs[16][65];

    int tid = threadIdx.x;
    int tx = tid & 15, ty = tid >> 4;
    int m0 = blockIdx.y * 64, n0 = blockIdx.x * 64;

    float c[4][4] = {};

    for (int k0 = 0; k0 < Kk; k0 += 16) {
        #pragma unroll
        for (int i = 0; i < 4; i++) {
            int e = tid + i * 256;
            int k = e & 15, m = e >> 4;
            As[k][m] = A[(size_t)(m0 + m) * Kk + k0 + k];
        }
        #pragma unroll
        for (int i = 0; i < 4; i++) {
            int e = tid + i * 256;
            int k = e & 15, n = e >> 4;
            Bs[k][n] = (n0 + n < Nn) ? Bw[(size_t)(n0 + n) * Kk + k0 + k] : 0.f;
        }
        __syncthreads();
        #pragma unroll
        for (int kk = 0; kk < 16; kk++) {
            float a[4], b[4];
            #pragma unroll
            for (int i = 0; i < 4; i++) a[i] = As[kk][ty * 4 + i];
            #pragma unroll
            for (int j = 0; j < 4; j++) b[j] = Bs[kk][tx * 4 + j];
            #pragma unroll
            for (int i = 0; i < 4; i++)
                #pragma unroll
                for (int j = 0; j < 4; j++)
                    c[i][j] = fmaf(a[i], b[j], c[i][j]);
        }
        __syncthreads();
    }

    #pragma unroll
    for (int i = 0; i < 4; i++) {
        int m = m0 + ty * 4 + i;
        #pragma unroll
        for (int j = 0; j < 4; j++) {
            int n = n0 + tx * 4 + j;
            if (n < Nn) {
                float v = c[i][j];
                if (HAS_BIAS) v += bias[n];
                if (GELU)     v = 0.5f * v * (1.f + erff(v * 0.70710678118654752f));
                if (RESID)    v += resid[(size_t)m * Nn + n];
                C[(size_t)m * Nn + n] = v;
            }
        }
    }
}

// ---------------------------------------------------------------------------
// Kernel 4: non-causal flash attention over qkv buffer [B, L, 3D]
// q at [0,D), k at [D,2D), v at [2D,3D); head hh occupies cols hh*64..hh*64+63.
// grid: (L/32, H, B); block 256 threads = 32 rows x 8 threads.
// scores scaled by 1/sqrt(64) = 0.125, softmax over all 2048 keys.
// ---------------------------------------------------------------------------
__global__ __launch_bounds__(256)
void attn_kernel(const float* __restrict__ qkv, float* __restrict__ o)
{
    const int QB = 32, KB = 64;
    int qt = blockIdx.x, hh = blockIdx.y, b = blockIdx.z;
    int t = threadIdx.x;
    int r = t >> 3;        // query row within tile: 0..31
    int sub = t & 7;       // 8 threads per row

    __shared__ float Q[QB][HDIM];
    __shared__ float Kx[KB][HDIM];
    __shared__ float Vx[KB][HDIM];
    __shared__ float P[QB][KB];

    for (int e = t; e < QB * HDIM; e += 256) {
        int qr = e >> 6, d = e & 63;
        Q[qr][d] = qkv[(size_t)(b * LL + qt * QB + qr) * (3 * DD) + hh * HDIM + d];
    }
    __syncthreads();

    float m_run = -1e30f, l_run = 0.f;
    float acc[8];
    #pragma unroll
    for (int i = 0; i < 8; i++) acc[i] = 0.f;

    for (int kb = 0; kb < LL / KB; kb++) {
        for (int e = t; e < KB * HDIM; e += 256) {
            int kr = e >> 6, d = e & 63;
            size_t base = (size_t)(b * LL + kb * KB + kr) * (3 * DD);
            Kx[kr][d] = qkv[base + DD + hh * HDIM + d];
            Vx[kr][d] = qkv[base + 2 * DD + hh * HDIM + d];
        }
        __syncthreads();

        float s[8];
        float mloc = -1e30f;
        #pragma unroll
        for (int j = 0; j < 8; j++) {
            int key = sub * 8 + j;
            float dot = 0.f;
            #pragma unroll
            for (int d = 0; d < HDIM; d++) dot = fmaf(Q[r][d], Kx[key][d], dot);
            s[j] = dot * 0.125f;
            mloc = fmaxf(mloc, s[j]);
        }
        #pragma unroll
        for (int off = 1; off < 8; off <<= 1) mloc = fmaxf(mloc, __shfl_xor(mloc, off));
        float m_new = fmaxf(m_run, mloc);
        float scale = expf(m_run - m_new);
        float psum = 0.f;
        #pragma unroll
        for (int j = 0; j < 8; j++) {
            float p = expf(s[j] - m_new);
            P[r][sub * 8 + j] = p;
            psum += p;
        }
        #pragma unroll
        for (int off = 1; off < 8; off <<= 1) psum += __shfl_xor(psum, off);
        l_run = l_run * scale + psum;
        m_run = m_new;
        #pragma unroll
        for (int i = 0; i < 8; i++) acc[i] *= scale;
        __syncthreads();   // make P visible

        for (int k = 0; k < KB; k++) {
            float p = P[r][k];
            #pragma unroll
            for (int i = 0; i < 8; i++) acc[i] = fmaf(p, Vx[k][sub * 8 + i], acc[i]);
        }
        __syncthreads();   // before overwriting Kx/Vx/P
    }

    float inv = 1.f / l_run;
    #pragma unroll
    for (int i = 0; i < 8; i++) {
        o[(size_t)(b * LL + qt * QB + r) * DD + hh * HDIM + sub * 8 + i] = acc[i] * inv;
    }
}

// ---------------------------------------------------------------------------
// Driver
// ---------------------------------------------------------------------------
extern "C" void kernel_launch(void* const* d_in, const int* in_sizes, int n_in,
                              void* d_out, int out_size, void* d_ws, size_t ws_size,
                              hipStream_t stream)
{
    const float* emb    = (const float*)d_in[0];
    const float* ent_w  = (const float*)d_in[1];
    const float* ent_b  = (const float*)d_in[2];
    const float* qkv_w  = (const float*)d_in[3];
    const float* qkv_b  = (const float*)d_in[4];
    const float* ao_w   = (const float*)d_in[5];
    const float* ao_b   = (const float*)d_in[6];
    const float* ln1_s  = (const float*)d_in[7];
    const float* ln1_b  = (const float*)d_in[8];
    const float* ln2_s  = (const float*)d_in[9];
    const float* ln2_b  = (const float*)d_in[10];
    const float* ff1_w  = (const float*)d_in[11];
    const float* ff1_b  = (const float*)d_in[12];
    const float* ff2_w  = (const float*)d_in[13];
    const float* ff2_b  = (const float*)d_in[14];
    const float* out_w  = (const float*)d_in[15];
    const int*   x      = (const int*)d_in[16];
    // d_in[17] = patch_lengths : dead code in the reference

    float* out = (float*)d_out;

    // workspace layout (f32): h, g, o : MM*DD each; big : MM*4*DD (qkv / ffn)
    float* h   = (float*)d_ws;
    float* g   = h + (size_t)MM * DD;
    float* o   = g + (size_t)MM * DD;
    float* big = o + (size_t)MM * DD;   // holds qkv [MM,3D] then ffn [MM,4D]

    dim3 blk(256);

    embed_ent_kernel<<<MM, blk, 0, stream>>>(x, emb, ent_w, ent_b, h);

    for (int layer = 0; layer < NLAYER; layer++) {
        const float* qw  = qkv_w + (size_t)layer * 3 * DD * DD;
        const float* qb  = qkv_b + (size_t)layer * 3 * DD;
        const float* aw  = ao_w  + (size_t)layer * DD * DD;
        const float* ab  = ao_b  + (size_t)layer * DD;
        const float* l1s = ln1_s + (size_t)layer * DD;
        const float* l1b = ln1_b + (size_t)layer * DD;
        const float* l2s = ln2_s + (size_t)layer * DD;
        const float* l2b = ln2_b + (size_t)layer * DD;
        const float* f1w = ff1_w + (size_t)layer * 4 * DD * DD;
        const float* f1b = ff1_b + (size_t)layer * 4 * DD;
        const float* f2w = ff2_w + (size_t)layer * DD * 4 * DD;
        const float* f2b = ff2_b + (size_t)layer * DD;

        // LN1
        ln_kernel<<<MM, blk, 0, stream>>>(h, l1s, l1b, g);

        // qkv = g @ qw^T + qb   [MM, 1536]
        {
            dim3 grid((3 * DD) / 64, MM / 64);
            gemm_nt<true, false, false><<<grid, blk, 0, stream>>>(
                g, qw, qb, nullptr, big, 3 * DD, DD);
        }

        // attention -> o [MM, DD]
        {
            dim3 grid(LL / 32, HH, BB);
            attn_kernel<<<grid, blk, 0, stream>>>(big, o);
        }

        // h = h + o @ aw^T + ab
        {
            dim3 grid(DD / 64, MM / 64);
            gemm_nt<true, false, true><<<grid, blk, 0, stream>>>(
                o, aw, ab, h, h, DD, DD);
        }

        // LN2
        ln_kernel<<<MM, blk, 0, stream>>>(h, l2s, l2b, g);

        // ffn1: big = gelu(g @ f1w^T + f1b)   [MM, 2048]
        {
            dim3 grid((4 * DD) / 64, MM / 64);
            gemm_nt<true, true, false><<<grid, blk, 0, stream>>>(
                g, f1w, f1b, nullptr, big, 4 * DD, DD);
        }

        // ffn2: h = h + big @ f2w^T + f2b   [MM, 512]
        {
            dim3 grid(DD / 64, MM / 64);
            gemm_nt<true, false, true><<<grid, blk, 0, stream>>>(
                big, f2w, f2b, h, h, DD, 4 * DD);
        }
    }

    // logits = h @ out_w^T   [MM, 258]
    {
        dim3 grid((VV + 63) / 64, MM / 64);
        gemm_nt<false, false, false><<<grid, blk, 0, stream>>>(
            h, out_w, nullptr, nullptr, out, VV, DD);
    }
}

// Round 3
// 1293.575 us; speedup vs baseline: 10.9463x; 10.9463x over previous
//
#include <hip/hip_runtime.h>
#include <hip/hip_bf16.h>
#include <math.h>

// Problem constants
#define BB 4
#define LL 2048
#define DD 512
#define HH 8
#define NLAYER 4
#define VV 258
#define WW 8
#define HDIM 64
#define MM (BB * LL)   // 8192 rows

typedef __attribute__((ext_vector_type(8))) short short8v;
typedef __attribute__((ext_vector_type(4))) float float4v;

__device__ __forceinline__ unsigned short f2bf(float x) {
    unsigned int u = __float_as_uint(x);
    unsigned int r = (u + 0x7fffu + ((u >> 16) & 1u)) >> 16;
    return (unsigned short)r;
}

// ---------------------------------------------------------------------------
// fp32 -> bf16 bulk convert (weights), n % 4 == 0
// ---------------------------------------------------------------------------
__global__ __launch_bounds__(256)
void cvt_kernel(const float* __restrict__ in, unsigned short* __restrict__ out, int n)
{
    int i = (blockIdx.x * 256 + threadIdx.x) * 4;
    if (i < n) {
        float4 v = *reinterpret_cast<const float4*>(in + i);
        uint2 pk;
        pk.x = (unsigned)f2bf(v.x) | ((unsigned)f2bf(v.y) << 16);
        pk.y = (unsigned)f2bf(v.z) | ((unsigned)f2bf(v.w) << 16);
        *reinterpret_cast<uint2*>(out + i) = pk;
    }
}

// ---------------------------------------------------------------------------
// Kernel 1: token embedding + sliding-window byte-entropy feature (fp32 out)
// values >= 256 contribute nothing (reference one_hot has 256 classes).
// ---------------------------------------------------------------------------
__global__ __launch_bounds__(256)
void embed_ent_kernel(const int* __restrict__ x,
                      const float* __restrict__ emb,
                      const float* __restrict__ ent_w,
                      const float* __restrict__ ent_b,
                      float* __restrict__ h)
{
    int row = blockIdx.x;            // 0..MM-1
    int b = row / LL, l = row % LL;

    float ent = 0.f;
    if (l <= LL - WW) {
        int win[WW];
        #pragma unroll
        for (int i = 0; i < WW; i++) win[i] = x[b * LL + l + i];
        float s = 0.f;
        #pragma unroll
        for (int i = 0; i < WW; i++) {
            if (win[i] < 256) {
                int c = 0;
                #pragma unroll
                for (int j = 0; j < WW; j++) c += (win[j] == win[i]) ? 1 : 0;
                s += log2f((float)c * 0.125f + 1e-10f);
            }
        }
        ent = -s * 0.125f;
    }

    int tok = x[b * LL + l];
    const float* erow = emb + (size_t)tok * DD;
    float* hrow = h + (size_t)row * DD;
    for (int d = threadIdx.x; d < DD; d += blockDim.x) {
        hrow[d] = erow[d] + ent * ent_w[d] + ent_b[d];
    }
}

// ---------------------------------------------------------------------------
// Kernel 2: LayerNorm (fp32 in, bf16 out)
// ---------------------------------------------------------------------------
__global__ __launch_bounds__(256)
void ln_kernel(const float* __restrict__ h,
               const float* __restrict__ scale,
               const float* __restrict__ bias,
               unsigned short* __restrict__ g)
{
    int row = blockIdx.x;
    const float* hr = h + (size_t)row * DD;
    unsigned short* gr = g + (size_t)row * DD;

    float sum = 0.f, sumsq = 0.f;
    for (int d = threadIdx.x; d < DD; d += 256) {
        float v = hr[d];
        sum += v; sumsq += v * v;
    }
    #pragma unroll
    for (int off = 32; off > 0; off >>= 1) {
        sum   += __shfl_down(sum, off);
        sumsq += __shfl_down(sumsq, off);
    }
    __shared__ float red0[4], red1[4];
    int wid = threadIdx.x >> 6, lane = threadIdx.x & 63;
    if (lane == 0) { red0[wid] = sum; red1[wid] = sumsq; }
    __syncthreads();
    if (threadIdx.x == 0) {
        float a = 0.f, q = 0.f;
        #pragma unroll
        for (int i = 0; i < 4; i++) { a += red0[i]; q += red1[i]; }
        red0[0] = a; red1[0] = q;
    }
    __syncthreads();
    float mu = red0[0] * (1.f / DD);
    float var = red1[0] * (1.f / DD) - mu * mu;
    float rstd = rsqrtf(var + 1e-5f);

    for (int d = threadIdx.x; d < DD; d += 256) {
        gr[d] = f2bf((hr[d] - mu) * rstd * scale[d] + bias[d]);
    }
}

// ---------------------------------------------------------------------------
// Kernel 3: MFMA GEMM  C[M,N] = A[M,K](bf16) * W[N,K]^T(bf16)
// 128x128 tile, BK=64, 256 threads (4 waves, 2x2 of 64x64), 16x16x32 bf16.
// LDS xor-swizzle ((row&7)<<4) on both ds_write_b128 and ds_read_b128.
// Epilogue: +bias(f32), gelu, +resid(f32); out f32 or bf16.
// ---------------------------------------------------------------------------
template<bool HAS_BIAS, bool GELU, bool RESID, bool OUT_BF16>
__global__ __launch_bounds__(256)
void gemm_mfma(const unsigned short* __restrict__ A,
               const unsigned short* __restrict__ W,
               const float* __restrict__ bias,
               const float* __restrict__ resid,
               void* __restrict__ Cv,
               int Nn, int Kk)
{
    __shared__ unsigned short As[128 * 64];
    __shared__ unsigned short Bs[128 * 64];

    int t = threadIdx.x;
    int w = t >> 6, lane = t & 63;
    int wr = w >> 1, wc = w & 1;
    int l15 = lane & 15, l4 = lane >> 4;
    int m0 = blockIdx.y * 128, n0 = blockIdx.x * 128;

    float4v acc[4][4];
    #pragma unroll
    for (int i = 0; i < 4; i++)
        #pragma unroll
        for (int j = 0; j < 4; j++)
            acc[i][j] = (float4v){0.f, 0.f, 0.f, 0.f};

    for (int k0 = 0; k0 < Kk; k0 += 64) {
        short8v ar[4], br[4];
        #pragma unroll
        for (int i = 0; i < 4; i++) {
            int c = t + i * 256;
            int row = c >> 3, seg = c & 7;
            ar[i] = *reinterpret_cast<const short8v*>(A + (size_t)(m0 + row) * Kk + k0 + seg * 8);
            br[i] = *reinterpret_cast<const short8v*>(W + (size_t)(n0 + row) * Kk + k0 + seg * 8);
        }
        __syncthreads();
        #pragma unroll
        for (int i = 0; i < 4; i++) {
            int c = t + i * 256;
            int row = c >> 3, seg = c & 7;
            int off = (row * 128 + seg * 16) ^ ((row & 7) << 4);
            *reinterpret_cast<short8v*>((char*)As + off) = ar[i];
            *reinterpret_cast<short8v*>((char*)Bs + off) = br[i];
        }
        __syncthreads();
        #pragma unroll
        for (int kc = 0; kc < 2; kc++) {
            short8v af[4], bfr[4];
            #pragma unroll
            for (int mf = 0; mf < 4; mf++) {
                int row = wr * 64 + mf * 16 + l15;
                int off = (row * 128 + kc * 64 + l4 * 16) ^ ((row & 7) << 4);
                af[mf] = *reinterpret_cast<const short8v*>((const char*)As + off);
            }
            #pragma unroll
            for (int nf = 0; nf < 4; nf++) {
                int row = wc * 64 + nf * 16 + l15;
                int off = (row * 128 + kc * 64 + l4 * 16) ^ ((row & 7) << 4);
                bfr[nf] = *reinterpret_cast<const short8v*>((const char*)Bs + off);
            }
            #pragma unroll
            for (int mf = 0; mf < 4; mf++)
                #pragma unroll
                for (int nf = 0; nf < 4; nf++)
                    acc[mf][nf] = __builtin_amdgcn_mfma_f32_16x16x32_bf16(
                        af[mf], bfr[nf], acc[mf][nf], 0, 0, 0);
        }
    }

    #pragma unroll
    for (int mf = 0; mf < 4; mf++)
        #pragma unroll
        for (int nf = 0; nf < 4; nf++)
            #pragma unroll
            for (int r = 0; r < 4; r++) {
                int m = m0 + wr * 64 + mf * 16 + l4 * 4 + r;
                int n = n0 + wc * 64 + nf * 16 + l15;
                float v = acc[mf][nf][r];
                if (HAS_BIAS) v += bias[n];
                if (GELU)     v = 0.5f * v * (1.f + erff(v * 0.70710678118654752f));
                if (RESID)    v += resid[(size_t)m * Nn + n];
                if (OUT_BF16) ((unsigned short*)Cv)[(size_t)m * Nn + n] = f2bf(v);
                else          ((float*)Cv)[(size_t)m * Nn + n] = v;
            }
}

// ---------------------------------------------------------------------------
// Kernel 4: MFMA flash attention (bf16 qkv in, bf16 o out)
// grid (L/64, H, B); 256 threads = 4 waves x 16 q-rows; KB=64 key tiles.
// K staged xor-swizzled; V staged transposed Vt[d][72]; P via per-wave LDS.
// ---------------------------------------------------------------------------
__global__ __launch_bounds__(256)
void attn_mfma(const unsigned short* __restrict__ qkv, unsigned short* __restrict__ o)
{
    __shared__ unsigned short Kl[64 * 64];     // [key][d] swizzled
    __shared__ unsigned short Vt[64 * 72];     // [d][key], padded stride 72
    __shared__ unsigned short Pl[4 * 16 * 64]; // per-wave [q][key]

    int t = threadIdx.x, w = t >> 6, lane = t & 63;
    int l15 = lane & 15, l4 = lane >> 4;
    int qt = blockIdx.x, hh = blockIdx.y, b = blockIdx.z;
    int q0 = qt * 64 + w * 16;
    const int RS = 3 * DD; // 1536

    // Q fragments (A-operand), hoisted: rows q0+l15, k = dh*32 + l4*8 + j
    short8v qf[2];
    #pragma unroll
    for (int dh = 0; dh < 2; dh++) {
        size_t addr = (size_t)(b * LL + q0 + l15) * RS + hh * HDIM + dh * 32 + l4 * 8;
        qf[dh] = *reinterpret_cast<const short8v*>(qkv + addr);
    }

    float4v o_acc[4];
    #pragma unroll
    for (int dt = 0; dt < 4; dt++) o_acc[dt] = (float4v){0.f, 0.f, 0.f, 0.f};
    float m_run[4], l_run[4];
    #pragma unroll
    for (int r = 0; r < 4; r++) { m_run[r] = -1e30f; l_run[r] = 0.f; }

    char* pbase = (char*)Pl + w * 2048;

    for (int kb = 0; kb < LL / 64; kb++) {
        // global loads (issue early, write after barrier)
        short8v krg[2], vrg[2];
        #pragma unroll
        for (int i = 0; i < 2; i++) {
            int c = t + i * 256;
            int row = c >> 3, seg = c & 7;
            size_t ga = (size_t)(b * LL + kb * 64 + row) * RS + hh * HDIM + seg * 8;
            krg[i] = *reinterpret_cast<const short8v*>(qkv + ga + DD);
            vrg[i] = *reinterpret_cast<const short8v*>(qkv + ga + 2 * DD);
        }
        __syncthreads();   // previous tile's compute done
        #pragma unroll
        for (int i = 0; i < 2; i++) {
            int c = t + i * 256;
            int row = c >> 3, seg = c & 7;
            int off = (row * 128 + seg * 16) ^ ((row & 7) << 4);
            *reinterpret_cast<short8v*>((char*)Kl + off) = krg[i];
            int d0 = seg * 8;
            #pragma unroll
            for (int e = 0; e < 8; e++)
                Vt[(d0 + e) * 72 + row] = (unsigned short)vrg[i][e];
        }
        __syncthreads();

        // S = Q K^T : C[m=q][n=key], accumulate over both d-halves
        float4v s_acc[4];
        #pragma unroll
        for (int nt = 0; nt < 4; nt++) {
            s_acc[nt] = (float4v){0.f, 0.f, 0.f, 0.f};
            #pragma unroll
            for (int dh = 0; dh < 2; dh++) {
                int row = nt * 16 + l15;
                int off = (row * 128 + dh * 64 + l4 * 16) ^ ((row & 7) << 4);
                short8v kf = *reinterpret_cast<const short8v*>((const char*)Kl + off);
                s_acc[nt] = __builtin_amdgcn_mfma_f32_16x16x32_bf16(qf[dh], kf, s_acc[nt], 0, 0, 0);
            }
        }

        // online softmax per q-row r (rows spread over 16-lane groups)
        #pragma unroll
        for (int r = 0; r < 4; r++) {
            float mm = fmaxf(fmaxf(s_acc[0][r], s_acc[1][r]),
                             fmaxf(s_acc[2][r], s_acc[3][r])) * 0.125f;
            #pragma unroll
            for (int o_ = 1; o_ < 16; o_ <<= 1) mm = fmaxf(mm, __shfl_xor(mm, o_));
            float mnew = fmaxf(m_run[r], mm);
            float sc = __expf(m_run[r] - mnew);
            m_run[r] = mnew;
            float ps = 0.f;
            int q = l4 * 4 + r;
            #pragma unroll
            for (int nt = 0; nt < 4; nt++) {
                float p = __expf(s_acc[nt][r] * 0.125f - mnew);
                ps += p;
                int off = (q * 128 + nt * 32 + l15 * 2) ^ ((q & 7) << 4);
                *reinterpret_cast<unsigned short*>(pbase + off) = f2bf(p);
            }
            #pragma unroll
            for (int o_ = 1; o_ < 16; o_ <<= 1) ps += __shfl_xor(ps, o_);
            l_run[r] = l_run[r] * sc + ps;
            #pragma unroll
            for (int dt = 0; dt < 4; dt++) o_acc[dt][r] *= sc;
        }

        // O += P V : A-frag = P (re-read from wave-private LDS), B-frag = Vt rows
        #pragma unroll
        for (int kc = 0; kc < 2; kc++) {
            int poff = (l15 * 128 + kc * 64 + l4 * 16) ^ ((l15 & 7) << 4);
            short8v pf = *reinterpret_cast<const short8v*>(pbase + poff);
            #pragma unroll
            for (int dt = 0; dt < 4; dt++) {
                int d = dt * 16 + l15;
                short8v vf = *reinterpret_cast<const short8v*>(
                    (const char*)Vt + d * 144 + kc * 64 + l4 * 16);
                o_acc[dt] = __builtin_amdgcn_mfma_f32_16x16x32_bf16(pf, vf, o_acc[dt], 0, 0, 0);
            }
        }
    }

    #pragma unroll
    for (int r = 0; r < 4; r++) {
        float inv = 1.f / l_run[r];
        int qg = q0 + l4 * 4 + r;
        #pragma unroll
        for (int dt = 0; dt < 4; dt++) {
            o[(size_t)(b * LL + qg) * DD + hh * HDIM + dt * 16 + l15] =
                f2bf(o_acc[dt][r] * inv);
        }
    }
}

// ---------------------------------------------------------------------------
// fp32 SIMT GEMM (logits only, N=258): C = A[M,K] * W[N,K]^T
// ---------------------------------------------------------------------------
__global__ __launch_bounds__(256)
void gemm_nt_f32(const float* __restrict__ A,
                 const float* __restrict__ Bw,
                 float* __restrict__ C,
                 int Nn, int Kk)
{
    __shared__ float As[16][65];
    __shared__ float Bs[16][65];

    int tid = threadIdx.x;
    int tx = tid & 15, ty = tid >> 4;
    int m0 = blockIdx.y * 64, n0 = blockIdx.x * 64;

    float c[4][4] = {};

    for (int k0 = 0; k0 < Kk; k0 += 16) {
        #pragma unroll
        for (int i = 0; i < 4; i++) {
            int e = tid + i * 256;
            int k = e & 15, m = e >> 4;
            As[k][m] = A[(size_t)(m0 + m) * Kk + k0 + k];
        }
        #pragma unroll
        for (int i = 0; i < 4; i++) {
            int e = tid + i * 256;
            int k = e & 15, n = e >> 4;
            Bs[k][n] = (n0 + n < Nn) ? Bw[(size_t)(n0 + n) * Kk + k0 + k] : 0.f;
        }
        __syncthreads();
        #pragma unroll
        for (int kk = 0; kk < 16; kk++) {
            float a[4], b[4];
            #pragma unroll
            for (int i = 0; i < 4; i++) a[i] = As[kk][ty * 4 + i];
            #pragma unroll
            for (int j = 0; j < 4; j++) b[j] = Bs[kk][tx * 4 + j];
            #pragma unroll
            for (int i = 0; i < 4; i++)
                #pragma unroll
                for (int j = 0; j < 4; j++)
                    c[i][j] = fmaf(a[i], b[j], c[i][j]);
        }
        __syncthreads();
    }

    #pragma unroll
    for (int i = 0; i < 4; i++) {
        int m = m0 + ty * 4 + i;
        #pragma unroll
        for (int j = 0; j < 4; j++) {
            int n = n0 + tx * 4 + j;
            if (n < Nn) C[(size_t)m * Nn + n] = c[i][j];
        }
    }
}

// ---------------------------------------------------------------------------
// Driver
// ---------------------------------------------------------------------------
extern "C" void kernel_launch(void* const* d_in, const int* in_sizes, int n_in,
                              void* d_out, int out_size, void* d_ws, size_t ws_size,
                              hipStream_t stream)
{
    const float* emb    = (const float*)d_in[0];
    const float* ent_w  = (const float*)d_in[1];
    const float* ent_b  = (const float*)d_in[2];
    const float* qkv_w  = (const float*)d_in[3];
    const float* qkv_b  = (const float*)d_in[4];
    const float* ao_w   = (const float*)d_in[5];
    const float* ao_b   = (const float*)d_in[6];
    const float* ln1_s  = (const float*)d_in[7];
    const float* ln1_b  = (const float*)d_in[8];
    const float* ln2_s  = (const float*)d_in[9];
    const float* ln2_b  = (const float*)d_in[10];
    const float* ff1_w  = (const float*)d_in[11];
    const float* ff1_b  = (const float*)d_in[12];
    const float* ff2_w  = (const float*)d_in[13];
    const float* ff2_b  = (const float*)d_in[14];
    const float* out_w  = (const float*)d_in[15];
    const int*   x      = (const int*)d_in[16];
    // d_in[17] = patch_lengths : dead code in the reference

    float* out = (float*)d_out;

    const int NQW = NLAYER * 3 * DD * DD;   // 3,145,728
    const int NAW = NLAYER * DD * DD;       // 1,048,576
    const int NF1 = NLAYER * 4 * DD * DD;   // 4,194,304
    const int NF2 = NLAYER * DD * 4 * DD;   // 4,194,304

    char* p = (char*)d_ws;
    unsigned short* wq = (unsigned short*)p; p += (size_t)NQW * 2;
    unsigned short* wa = (unsigned short*)p; p += (size_t)NAW * 2;
    unsigned short* w1 = (unsigned short*)p; p += (size_t)NF1 * 2;
    unsigned short* w2 = (unsigned short*)p; p += (size_t)NF2 * 2;
    float*          h  = (float*)p;          p += (size_t)MM * DD * 4;
    unsigned short* gb = (unsigned short*)p; p += (size_t)MM * DD * 2;
    unsigned short* ob = (unsigned short*)p; p += (size_t)MM * DD * 2;
    unsigned short* bb = (unsigned short*)p; p += (size_t)MM * 4 * DD * 2; // qkv / ffn

    dim3 blk(256);

    // weight conversion (stateless, every launch)
    cvt_kernel<<<NQW / 1024, blk, 0, stream>>>(qkv_w, wq, NQW);
    cvt_kernel<<<NAW / 1024, blk, 0, stream>>>(ao_w,  wa, NAW);
    cvt_kernel<<<NF1 / 1024, blk, 0, stream>>>(ff1_w, w1, NF1);
    cvt_kernel<<<NF2 / 1024, blk, 0, stream>>>(ff2_w, w2, NF2);

    embed_ent_kernel<<<MM, blk, 0, stream>>>(x, emb, ent_w, ent_b, h);

    for (int layer = 0; layer < NLAYER; layer++) {
        const unsigned short* qw = wq + (size_t)layer * 3 * DD * DD;
        const unsigned short* aw = wa + (size_t)layer * DD * DD;
        const unsigned short* f1 = w1 + (size_t)layer * 4 * DD * DD;
        const unsigned short* f2 = w2 + (size_t)layer * DD * 4 * DD;
        const float* qb  = qkv_b + (size_t)layer * 3 * DD;
        const float* ab  = ao_b  + (size_t)layer * DD;
        const float* l1s = ln1_s + (size_t)layer * DD;
        const float* l1b = ln1_b + (size_t)layer * DD;
        const float* l2s = ln2_s + (size_t)layer * DD;
        const float* l2b = ln2_b + (size_t)layer * DD;
        const float* f1b = ff1_b + (size_t)layer * 4 * DD;
        const float* f2b = ff2_b + (size_t)layer * DD;

        // LN1: h -> gb (bf16)
        ln_kernel<<<MM, blk, 0, stream>>>(h, l1s, l1b, gb);

        // qkv = gb @ qw^T + qb -> bb (bf16) [MM,1536]
        {
            dim3 grid((3 * DD) / 128, MM / 128);
            gemm_mfma<true, false, false, true><<<grid, blk, 0, stream>>>(
                gb, qw, qb, nullptr, bb, 3 * DD, DD);
        }

        // attention: bb -> ob (bf16)
        {
            dim3 grid(LL / 64, HH, BB);
            attn_mfma<<<grid, blk, 0, stream>>>(bb, ob);
        }

        // h = h + ob @ aw^T + ab  (f32 out)
        {
            dim3 grid(DD / 128, MM / 128);
            gemm_mfma<true, false, true, false><<<grid, blk, 0, stream>>>(
                ob, aw, ab, h, h, DD, DD);
        }

        // LN2: h -> gb
        ln_kernel<<<MM, blk, 0, stream>>>(h, l2s, l2b, gb);

        // ffn1: bb = gelu(gb @ f1^T + f1b) (bf16) [MM,2048]
        {
            dim3 grid((4 * DD) / 128, MM / 128);
            gemm_mfma<true, true, false, true><<<grid, blk, 0, stream>>>(
                gb, f1, f1b, nullptr, bb, 4 * DD, DD);
        }

        // ffn2: h = h + bb @ f2^T + f2b  (f32 out)
        {
            dim3 grid(DD / 128, MM / 128);
            gemm_mfma<true, false, true, false><<<grid, blk, 0, stream>>>(
                bb, f2, f2b, h, h, DD, 4 * DD);
        }
    }

    // logits = h @ out_w^T   [MM, 258] (fp32 SIMT)
    {
        dim3 grid((VV + 63) / 64, MM / 64);
        gemm_nt_f32<<<grid, blk, 0, stream>>>(h, out_w, out, VV, DD);
    }
}

// Round 4
// 1056.461 us; speedup vs baseline: 13.4031x; 1.2244x over previous
//
#include <hip/hip_runtime.h>
#include <hip/hip_bf16.h>
#include <math.h>

// Problem constants
#define BB 4
#define LL 2048
#define DD 512
#define HH 8
#define NLAYER 4
#define VV 258
#define WW 8
#define HDIM 64
#define MM (BB * LL)   // 8192 rows

typedef __attribute__((ext_vector_type(8))) short short8v;
typedef __attribute__((ext_vector_type(4))) short short4v;
typedef __attribute__((ext_vector_type(4))) float float4v;

typedef __attribute__((address_space(3))) unsigned int lds_u32;
typedef const __attribute__((address_space(1))) unsigned int glb_u32;

__device__ __forceinline__ unsigned short f2bf(float x) {
    unsigned int u = __float_as_uint(x);
    unsigned int r = (u + 0x7fffu + ((u >> 16) & 1u)) >> 16;
    return (unsigned short)r;
}

// ---------------------------------------------------------------------------
// fp32 -> bf16 bulk convert (weights), n % 4 == 0
// ---------------------------------------------------------------------------
__global__ __launch_bounds__(256)
void cvt_kernel(const float* __restrict__ in, unsigned short* __restrict__ out, int n)
{
    int i = (blockIdx.x * 256 + threadIdx.x) * 4;
    if (i < n) {
        float4 v = *reinterpret_cast<const float4*>(in + i);
        uint2 pk;
        pk.x = (unsigned)f2bf(v.x) | ((unsigned)f2bf(v.y) << 16);
        pk.y = (unsigned)f2bf(v.z) | ((unsigned)f2bf(v.w) << 16);
        *reinterpret_cast<uint2*>(out + i) = pk;
    }
}

// ---------------------------------------------------------------------------
// Kernel 1: token embedding + sliding-window byte-entropy feature (fp32 out)
// values >= 256 contribute nothing (reference one_hot has 256 classes).
// ---------------------------------------------------------------------------
__global__ __launch_bounds__(256)
void embed_ent_kernel(const int* __restrict__ x,
                      const float* __restrict__ emb,
                      const float* __restrict__ ent_w,
                      const float* __restrict__ ent_b,
                      float* __restrict__ h)
{
    int row = blockIdx.x;            // 0..MM-1
    int b = row / LL, l = row % LL;

    float ent = 0.f;
    if (l <= LL - WW) {
        int win[WW];
        #pragma unroll
        for (int i = 0; i < WW; i++) win[i] = x[b * LL + l + i];
        float s = 0.f;
        #pragma unroll
        for (int i = 0; i < WW; i++) {
            if (win[i] < 256) {
                int c = 0;
                #pragma unroll
                for (int j = 0; j < WW; j++) c += (win[j] == win[i]) ? 1 : 0;
                s += log2f((float)c * 0.125f + 1e-10f);
            }
        }
        ent = -s * 0.125f;
    }

    int tok = x[b * LL + l];
    const float* erow = emb + (size_t)tok * DD;
    float* hrow = h + (size_t)row * DD;
    for (int d = threadIdx.x; d < DD; d += blockDim.x) {
        hrow[d] = erow[d] + ent * ent_w[d] + ent_b[d];
    }
}

// ---------------------------------------------------------------------------
// Kernel 2: LayerNorm (fp32 in, bf16 out)
// ---------------------------------------------------------------------------
__global__ __launch_bounds__(256)
void ln_kernel(const float* __restrict__ h,
               const float* __restrict__ scale,
               const float* __restrict__ bias,
               unsigned short* __restrict__ g)
{
    int row = blockIdx.x;
    const float* hr = h + (size_t)row * DD;
    unsigned short* gr = g + (size_t)row * DD;

    float sum = 0.f, sumsq = 0.f;
    for (int d = threadIdx.x; d < DD; d += 256) {
        float v = hr[d];
        sum += v; sumsq += v * v;
    }
    #pragma unroll
    for (int off = 32; off > 0; off >>= 1) {
        sum   += __shfl_down(sum, off);
        sumsq += __shfl_down(sumsq, off);
    }
    __shared__ float red0[4], red1[4];
    int wid = threadIdx.x >> 6, lane = threadIdx.x & 63;
    if (lane == 0) { red0[wid] = sum; red1[wid] = sumsq; }
    __syncthreads();
    if (threadIdx.x == 0) {
        float a = 0.f, q = 0.f;
        #pragma unroll
        for (int i = 0; i < 4; i++) { a += red0[i]; q += red1[i]; }
        red0[0] = a; red1[0] = q;
    }
    __syncthreads();
    float mu = red0[0] * (1.f / DD);
    float var = red1[0] * (1.f / DD) - mu * mu;
    float rstd = rsqrtf(var + 1e-5f);

    for (int d = threadIdx.x; d < DD; d += 256) {
        gr[d] = f2bf((hr[d] - mu) * rstd * scale[d] + bias[d]);
    }
}

// ---------------------------------------------------------------------------
// Kernel 3: MFMA GEMM  C[M,N] = A[M,K](bf16) * W[N,K]^T(bf16)
// 128x128 tile, BK=64, 256 threads (4 waves, 2x2 of 64x64), 16x16x32 bf16.
// Staging via global_load_lds width=16: linear LDS dest, pre-swizzled global
// source (seg ^= row&7), matching the read-side XOR swizzle ((row&7)<<4).
// Epilogue: +bias(f32), gelu, +resid(f32); out f32 or bf16.
// ---------------------------------------------------------------------------
template<bool HAS_BIAS, bool GELU, bool RESID, bool OUT_BF16>
__global__ __launch_bounds__(256)
void gemm_mfma(const unsigned short* __restrict__ A,
               const unsigned short* __restrict__ W,
               const float* __restrict__ bias,
               const float* __restrict__ resid,
               void* __restrict__ Cv,
               int Nn, int Kk)
{
    __shared__ unsigned short As[128 * 64];
    __shared__ unsigned short Bs[128 * 64];

    int t = threadIdx.x;
    int w = t >> 6, lane = t & 63;
    int wr = w >> 1, wc = w & 1;
    int l15 = lane & 15, l4 = lane >> 4;
    int m0 = blockIdx.y * 128, n0 = blockIdx.x * 128;

    int lrow = lane >> 3;              // 0..7 : row within the wave's 8-row slab
    int segp = (lane & 7) ^ lrow;      // pre-swizzled 16B-segment for global fetch

    float4v acc[4][4];
    #pragma unroll
    for (int i = 0; i < 4; i++)
        #pragma unroll
        for (int j = 0; j < 4; j++)
            acc[i][j] = (float4v){0.f, 0.f, 0.f, 0.f};

    for (int k0 = 0; k0 < Kk; k0 += 64) {
        if (k0) __syncthreads();       // previous compute done before overwrite
        #pragma unroll
        for (int i = 0; i < 4; i++) {
            int r = i * 32 + w * 8 + lrow;       // LDS-local row 0..127 (r&7 == lrow)
            __builtin_amdgcn_global_load_lds(
                (glb_u32*)(A + (size_t)(m0 + r) * Kk + k0 + segp * 8),
                (lds_u32*)(As + i * 2048 + w * 512), 16, 0, 0);
            __builtin_amdgcn_global_load_lds(
                (glb_u32*)(W + (size_t)(n0 + r) * Kk + k0 + segp * 8),
                (lds_u32*)(Bs + i * 2048 + w * 512), 16, 0, 0);
        }
        __syncthreads();               // drains vmcnt before barrier

        #pragma unroll
        for (int kc = 0; kc < 2; kc++) {
            short8v af[4], bfr[4];
            #pragma unroll
            for (int mf = 0; mf < 4; mf++) {
                int row = wr * 64 + mf * 16 + l15;
                int off = (row * 128 + kc * 64 + l4 * 16) ^ ((row & 7) << 4);
                af[mf] = *reinterpret_cast<const short8v*>((const char*)As + off);
            }
            #pragma unroll
            for (int nf = 0; nf < 4; nf++) {
                int row = wc * 64 + nf * 16 + l15;
                int off = (row * 128 + kc * 64 + l4 * 16) ^ ((row & 7) << 4);
                bfr[nf] = *reinterpret_cast<const short8v*>((const char*)Bs + off);
            }
            #pragma unroll
            for (int mf = 0; mf < 4; mf++)
                #pragma unroll
                for (int nf = 0; nf < 4; nf++)
                    acc[mf][nf] = __builtin_amdgcn_mfma_f32_16x16x32_bf16(
                        af[mf], bfr[nf], acc[mf][nf], 0, 0, 0);
        }
    }

    #pragma unroll
    for (int mf = 0; mf < 4; mf++)
        #pragma unroll
        for (int nf = 0; nf < 4; nf++)
            #pragma unroll
            for (int r = 0; r < 4; r++) {
                int m = m0 + wr * 64 + mf * 16 + l4 * 4 + r;
                int n = n0 + wc * 64 + nf * 16 + l15;
                float v = acc[mf][nf][r];
                if (HAS_BIAS) v += bias[n];
                if (GELU)     v = 0.5f * v * (1.f + erff(v * 0.70710678118654752f));
                if (RESID)    v += resid[(size_t)m * Nn + n];
                if (OUT_BF16) ((unsigned short*)Cv)[(size_t)m * Nn + n] = f2bf(v);
                else          ((float*)Cv)[(size_t)m * Nn + n] = v;
            }
}

// ---------------------------------------------------------------------------
// Kernel 4: MFMA flash attention (bf16 qkv in, bf16 o out)
// grid (L/64, H, B); 256 threads = 4 waves x 16 q-rows; KB=64 key tiles.
// Swapped QK^T: S^T = mfma(K, Q) -> lane owns 16 scores of q-row (q = lane&15)
// -> softmax needs only 2+2 shfls/tile and P-stores are 4x8B.
// K swizzled ((row&7)<<4); Vt[d][key] stride 144B swizzled (((d>>3)&7)<<4)
// (write pattern = exactly 2 lanes/bank, free per m136).
// ---------------------------------------------------------------------------
__global__ __launch_bounds__(256)
void attn_mfma(const unsigned short* __restrict__ qkv, unsigned short* __restrict__ o)
{
    __shared__ unsigned short Kl[64 * 64];     // [key][d] swizzled
    __shared__ unsigned short Vt[64 * 72];     // [d][key], stride 72 shorts, swizzled
    __shared__ unsigned short Pl[4 * 16 * 64]; // per-wave [q][key] swizzled
    __shared__ float Scl[4][16];               // per-wave per-q broadcast slot

    int t = threadIdx.x, w = t >> 6, lane = t & 63;
    int l15 = lane & 15, l4 = lane >> 4;
    int qt = blockIdx.x, hh = blockIdx.y, b = blockIdx.z;
    int q0 = qt * 64 + w * 16;
    const int RS = 3 * DD; // 1536

    // Q fragments (B-operand of swapped QK^T): rows q0+l15, k = dh*32 + l4*8 + j
    short8v qf[2];
    #pragma unroll
    for (int dh = 0; dh < 2; dh++) {
        size_t addr = (size_t)(b * LL + q0 + l15) * RS + hh * HDIM + dh * 32 + l4 * 8;
        qf[dh] = *reinterpret_cast<const short8v*>(qkv + addr);
    }

    float4v o_acc[4];
    #pragma unroll
    for (int dt = 0; dt < 4; dt++) o_acc[dt] = (float4v){0.f, 0.f, 0.f, 0.f};
    float m_run = -1e30f, l_run = 0.f;   // per-lane, for q = l15

    char* pbase = (char*)Pl + w * 2048;

    for (int kb = 0; kb < LL / 64; kb++) {
        // global loads (issue early, write after barrier)
        short8v krg[2], vrg[2];
        #pragma unroll
        for (int i = 0; i < 2; i++) {
            int c = t + i * 256;
            int row = c >> 3, seg = c & 7;
            size_t ga = (size_t)(b * LL + kb * 64 + row) * RS + hh * HDIM + seg * 8;
            krg[i] = *reinterpret_cast<const short8v*>(qkv + ga + DD);
            vrg[i] = *reinterpret_cast<const short8v*>(qkv + ga + 2 * DD);
        }
        __syncthreads();   // previous tile's compute done
        #pragma unroll
        for (int i = 0; i < 2; i++) {
            int c = t + i * 256;
            int row = c >> 3, seg = c & 7;
            int koff = (row * 128 + seg * 16) ^ ((row & 7) << 4);
            *reinterpret_cast<short8v*>((char*)Kl + koff) = krg[i];
            #pragma unroll
            for (int e = 0; e < 8; e++) {
                int d = seg * 8 + e;                 // (d>>3)&7 == seg
                int voff = (d * 144 + row * 2) ^ (seg << 4);
                *reinterpret_cast<unsigned short*>((char*)Vt + voff) =
                    (unsigned short)vrg[i][e];
            }
        }
        __syncthreads();

        // S^T = K Q^T : C[m=key][n=q]; lane holds keys nt*16 + l4*4 + r for q=l15
        float4v s_acc[4];
        #pragma unroll
        for (int nt = 0; nt < 4; nt++) {
            s_acc[nt] = (float4v){0.f, 0.f, 0.f, 0.f};
            #pragma unroll
            for (int dh = 0; dh < 2; dh++) {
                int row = nt * 16 + l15;
                int off = (row * 128 + dh * 64 + l4 * 16) ^ ((row & 7) << 4);
                short8v kf = *reinterpret_cast<const short8v*>((const char*)Kl + off);
                s_acc[nt] = __builtin_amdgcn_mfma_f32_16x16x32_bf16(kf, qf[dh], s_acc[nt], 0, 0, 0);
            }
        }

        // online softmax: all state per-lane for q = l15 (4 redundant l4 copies)
        float mm = -1e30f;
        #pragma unroll
        for (int nt = 0; nt < 4; nt++)
            #pragma unroll
            for (int r = 0; r < 4; r++)
                mm = fmaxf(mm, s_acc[nt][r]);
        mm *= 0.125f;
        mm = fmaxf(mm, __shfl_xor(mm, 16));
        mm = fmaxf(mm, __shfl_xor(mm, 32));
        float mnew = fmaxf(m_run, mm);
        float sc = __expf(m_run - mnew);
        m_run = mnew;

        float ps = 0.f;
        #pragma unroll
        for (int nt = 0; nt < 4; nt++) {
            float p0 = __expf(s_acc[nt][0] * 0.125f - mnew);
            float p1 = __expf(s_acc[nt][1] * 0.125f - mnew);
            float p2 = __expf(s_acc[nt][2] * 0.125f - mnew);
            float p3 = __expf(s_acc[nt][3] * 0.125f - mnew);
            ps += (p0 + p1) + (p2 + p3);
            short4v pk;
            pk[0] = (short)f2bf(p0); pk[1] = (short)f2bf(p1);
            pk[2] = (short)f2bf(p2); pk[3] = (short)f2bf(p3);
            int off = (l15 * 128 + nt * 32 + l4 * 8) ^ ((l15 & 7) << 4);
            *reinterpret_cast<short4v*>(pbase + off) = pk;
        }
        ps += __shfl_xor(ps, 16);
        ps += __shfl_xor(ps, 32);
        l_run = l_run * sc + ps;

        // broadcast per-q rescale to the o_acc lane domain (q = l4*4 + reg)
        if (l4 == 0) Scl[w][l15] = sc;
        float4 scv = *reinterpret_cast<const float4*>(&Scl[w][l4 * 4]);
        #pragma unroll
        for (int dt = 0; dt < 4; dt++) {
            o_acc[dt][0] *= scv.x; o_acc[dt][1] *= scv.y;
            o_acc[dt][2] *= scv.z; o_acc[dt][3] *= scv.w;
        }

        // O += P V : A-frag = P (from wave-private LDS), B-frag = Vt rows
        #pragma unroll
        for (int kc = 0; kc < 2; kc++) {
            int poff = (l15 * 128 + kc * 64 + l4 * 16) ^ ((l15 & 7) << 4);
            short8v pf = *reinterpret_cast<const short8v*>(pbase + poff);
            #pragma unroll
            for (int dt = 0; dt < 4; dt++) {
                int d = dt * 16 + l15;
                int voff = (d * 144 + kc * 64 + l4 * 16) ^ (((d >> 3) & 7) << 4);
                short8v vf = *reinterpret_cast<const short8v*>((const char*)Vt + voff);
                o_acc[dt] = __builtin_amdgcn_mfma_f32_16x16x32_bf16(pf, vf, o_acc[dt], 0, 0, 0);
            }
        }
    }

    // epilogue: broadcast 1/l_run into the o_acc lane domain
    if (l4 == 0) Scl[w][l15] = 1.f / l_run;
    float4 iv = *reinterpret_cast<const float4*>(&Scl[w][l4 * 4]);
    float invs[4] = {iv.x, iv.y, iv.z, iv.w};
    #pragma unroll
    for (int r = 0; r < 4; r++) {
        int qg = q0 + l4 * 4 + r;
        #pragma unroll
        for (int dt = 0; dt < 4; dt++) {
            o[(size_t)(b * LL + qg) * DD + hh * HDIM + dt * 16 + l15] =
                f2bf(o_acc[dt][r] * invs[r]);
        }
    }
}

// ---------------------------------------------------------------------------
// fp32 SIMT GEMM (logits only, N=258): C = A[M,K] * W[N,K]^T
// ---------------------------------------------------------------------------
__global__ __launch_bounds__(256)
void gemm_nt_f32(const float* __restrict__ A,
                 const float* __restrict__ Bw,
                 float* __restrict__ C,
                 int Nn, int Kk)
{
    __shared__ float As[16][65];
    __shared__ float Bs[16][65];

    int tid = threadIdx.x;
    int tx = tid & 15, ty = tid >> 4;
    int m0 = blockIdx.y * 64, n0 = blockIdx.x * 64;

    float c[4][4] = {};

    for (int k0 = 0; k0 < Kk; k0 += 16) {
        #pragma unroll
        for (int i = 0; i < 4; i++) {
            int e = tid + i * 256;
            int k = e & 15, m = e >> 4;
            As[k][m] = A[(size_t)(m0 + m) * Kk + k0 + k];
        }
        #pragma unroll
        for (int i = 0; i < 4; i++) {
            int e = tid + i * 256;
            int k = e & 15, n = e >> 4;
            Bs[k][n] = (n0 + n < Nn) ? Bw[(size_t)(n0 + n) * Kk + k0 + k] : 0.f;
        }
        __syncthreads();
        #pragma unroll
        for (int kk = 0; kk < 16; kk++) {
            float a[4], b[4];
            #pragma unroll
            for (int i = 0; i < 4; i++) a[i] = As[kk][ty * 4 + i];
            #pragma unroll
            for (int j = 0; j < 4; j++) b[j] = Bs[kk][tx * 4 + j];
            #pragma unroll
            for (int i = 0; i < 4; i++)
                #pragma unroll
                for (int j = 0; j < 4; j++)
                    c[i][j] = fmaf(a[i], b[j], c[i][j]);
        }
        __syncthreads();
    }

    #pragma unroll
    for (int i = 0; i < 4; i++) {
        int m = m0 + ty * 4 + i;
        #pragma unroll
        for (int j = 0; j < 4; j++) {
            int n = n0 + tx * 4 + j;
            if (n < Nn) C[(size_t)m * Nn + n] = c[i][j];
        }
    }
}

// ---------------------------------------------------------------------------
// Driver
// ---------------------------------------------------------------------------
extern "C" void kernel_launch(void* const* d_in, const int* in_sizes, int n_in,
                              void* d_out, int out_size, void* d_ws, size_t ws_size,
                              hipStream_t stream)
{
    const float* emb    = (const float*)d_in[0];
    const float* ent_w  = (const float*)d_in[1];
    const float* ent_b  = (const float*)d_in[2];
    const float* qkv_w  = (const float*)d_in[3];
    const float* qkv_b  = (const float*)d_in[4];
    const float* ao_w   = (const float*)d_in[5];
    const float* ao_b   = (const float*)d_in[6];
    const float* ln1_s  = (const float*)d_in[7];
    const float* ln1_b  = (const float*)d_in[8];
    const float* ln2_s  = (const float*)d_in[9];
    const float* ln2_b  = (const float*)d_in[10];
    const float* ff1_w  = (const float*)d_in[11];
    const float* ff1_b  = (const float*)d_in[12];
    const float* ff2_w  = (const float*)d_in[13];
    const float* ff2_b  = (const float*)d_in[14];
    const float* out_w  = (const float*)d_in[15];
    const int*   x      = (const int*)d_in[16];
    // d_in[17] = patch_lengths : dead code in the reference

    float* out = (float*)d_out;

    const int NQW = NLAYER * 3 * DD * DD;
    const int NAW = NLAYER * DD * DD;
    const int NF1 = NLAYER * 4 * DD * DD;
    const int NF2 = NLAYER * DD * 4 * DD;

    char* p = (char*)d_ws;
    unsigned short* wq = (unsigned short*)p; p += (size_t)NQW * 2;
    unsigned short* wa = (unsigned short*)p; p += (size_t)NAW * 2;
    unsigned short* w1 = (unsigned short*)p; p += (size_t)NF1 * 2;
    unsigned short* w2 = (unsigned short*)p; p += (size_t)NF2 * 2;
    float*          h  = (float*)p;          p += (size_t)MM * DD * 4;
    unsigned short* gb = (unsigned short*)p; p += (size_t)MM * DD * 2;
    unsigned short* ob = (unsigned short*)p; p += (size_t)MM * DD * 2;
    unsigned short* bb = (unsigned short*)p; p += (size_t)MM * 4 * DD * 2; // qkv / ffn

    dim3 blk(256);

    cvt_kernel<<<NQW / 1024, blk, 0, stream>>>(qkv_w, wq, NQW);
    cvt_kernel<<<NAW / 1024, blk, 0, stream>>>(ao_w,  wa, NAW);
    cvt_kernel<<<NF1 / 1024, blk, 0, stream>>>(ff1_w, w1, NF1);
    cvt_kernel<<<NF2 / 1024, blk, 0, stream>>>(ff2_w, w2, NF2);

    embed_ent_kernel<<<MM, blk, 0, stream>>>(x, emb, ent_w, ent_b, h);

    for (int layer = 0; layer < NLAYER; layer++) {
        const unsigned short* qw = wq + (size_t)layer * 3 * DD * DD;
        const unsigned short* aw = wa + (size_t)layer * DD * DD;
        const unsigned short* f1 = w1 + (size_t)layer * 4 * DD * DD;
        const unsigned short* f2 = w2 + (size_t)layer * DD * 4 * DD;
        const float* qb  = qkv_b + (size_t)layer * 3 * DD;
        const float* ab  = ao_b  + (size_t)layer * DD;
        const float* l1s = ln1_s + (size_t)layer * DD;
        const float* l1b = ln1_b + (size_t)layer * DD;
        const float* l2s = ln2_s + (size_t)layer * DD;
        const float* l2b = ln2_b + (size_t)layer * DD;
        const float* f1b = ff1_b + (size_t)layer * 4 * DD;
        const float* f2b = ff2_b + (size_t)layer * DD;

        // LN1: h -> gb (bf16)
        ln_kernel<<<MM, blk, 0, stream>>>(h, l1s, l1b, gb);

        // qkv = gb @ qw^T + qb -> bb (bf16) [MM,1536]
        {
            dim3 grid((3 * DD) / 128, MM / 128);
            gemm_mfma<true, false, false, true><<<grid, blk, 0, stream>>>(
                gb, qw, qb, nullptr, bb, 3 * DD, DD);
        }

        // attention: bb -> ob (bf16)
        {
            dim3 grid(LL / 64, HH, BB);
            attn_mfma<<<grid, blk, 0, stream>>>(bb, ob);
        }

        // h = h + ob @ aw^T + ab  (f32 out)
        {
            dim3 grid(DD / 128, MM / 128);
            gemm_mfma<true, false, true, false><<<grid, blk, 0, stream>>>(
                ob, aw, ab, h, h, DD, DD);
        }

        // LN2: h -> gb
        ln_kernel<<<MM, blk, 0, stream>>>(h, l2s, l2b, gb);

        // ffn1: bb = gelu(gb @ f1^T + f1b) (bf16) [MM,2048]
        {
            dim3 grid((4 * DD) / 128, MM / 128);
            gemm_mfma<true, true, false, true><<<grid, blk, 0, stream>>>(
                gb, f1, f1b, nullptr, bb, 4 * DD, DD);
        }

        // ffn2: h = h + bb @ f2^T + f2b  (f32 out)
        {
            dim3 grid(DD / 128, MM / 128);
            gemm_mfma<true, false, true, false><<<grid, blk, 0, stream>>>(
                bb, f2, f2b, h, h, DD, 4 * DD);
        }
    }

    // logits = h @ out_w^T   [MM, 258] (fp32 SIMT)
    {
        dim3 grid((VV + 63) / 64, MM / 64);
        gemm_nt_f32<<<grid, blk, 0, stream>>>(h, out_w, out, VV, DD);
    }
}

// Round 5
// 850.245 us; speedup vs baseline: 16.6539x; 1.2425x over previous
//
#include <hip/hip_runtime.h>
#include <hip/hip_bf16.h>
#include <math.h>

// Problem constants
#define BB 4
#define LL 2048
#define DD 512
#define HH 8
#define NLAYER 4
#define VV 258
#define WW 8
#define HDIM 64
#define MM (BB * LL)   // 8192 rows
#define VPAD 384       // logits weight rows padded to tile multiple

typedef __attribute__((ext_vector_type(8))) short short8v;
typedef __attribute__((ext_vector_type(4))) float float4v;

typedef __attribute__((address_space(3))) unsigned int lds_u32;
typedef const __attribute__((address_space(1))) unsigned int glb_u32;

__device__ __forceinline__ unsigned short f2bf(float x) {
    unsigned int u = __float_as_uint(x);
    unsigned int r = (u + 0x7fffu + ((u >> 16) & 1u)) >> 16;
    return (unsigned short)r;
}

// ---------------------------------------------------------------------------
// fp32 -> bf16 bulk convert, n % 4 == 0
// ---------------------------------------------------------------------------
__global__ __launch_bounds__(256)
void cvt_kernel(const float* __restrict__ in, unsigned short* __restrict__ out, int n)
{
    int i = (blockIdx.x * 256 + threadIdx.x) * 4;
    if (i < n) {
        float4 v = *reinterpret_cast<const float4*>(in + i);
        uint2 pk;
        pk.x = (unsigned)f2bf(v.x) | ((unsigned)f2bf(v.y) << 16);
        pk.y = (unsigned)f2bf(v.z) | ((unsigned)f2bf(v.w) << 16);
        *reinterpret_cast<uint2*>(out + i) = pk;
    }
}

// fp32 [rows_in, DD] -> bf16 [VPAD, DD], pad rows zeroed (every launch)
__global__ __launch_bounds__(256)
void cvt_pad_kernel(const float* __restrict__ in, unsigned short* __restrict__ out)
{
    int i = blockIdx.x * 256 + threadIdx.x;   // element index, grid covers VPAD*DD
    int row = i >> 9;
    out[i] = (row < VV) ? f2bf(in[i]) : (unsigned short)0;
}

// ---------------------------------------------------------------------------
// Kernel 1: token embedding + sliding-window byte-entropy feature (fp32 out)
// values >= 256 contribute nothing (reference one_hot has 256 classes).
// ---------------------------------------------------------------------------
__global__ __launch_bounds__(256)
void embed_ent_kernel(const int* __restrict__ x,
                      const float* __restrict__ emb,
                      const float* __restrict__ ent_w,
                      const float* __restrict__ ent_b,
                      float* __restrict__ h)
{
    int row = blockIdx.x;            // 0..MM-1
    int b = row / LL, l = row % LL;

    float ent = 0.f;
    if (l <= LL - WW) {
        int win[WW];
        #pragma unroll
        for (int i = 0; i < WW; i++) win[i] = x[b * LL + l + i];
        float s = 0.f;
        #pragma unroll
        for (int i = 0; i < WW; i++) {
            if (win[i] < 256) {
                int c = 0;
                #pragma unroll
                for (int j = 0; j < WW; j++) c += (win[j] == win[i]) ? 1 : 0;
                s += log2f((float)c * 0.125f + 1e-10f);
            }
        }
        ent = -s * 0.125f;
    }

    int tok = x[b * LL + l];
    const float* erow = emb + (size_t)tok * DD;
    float* hrow = h + (size_t)row * DD;
    for (int d = threadIdx.x; d < DD; d += blockDim.x) {
        hrow[d] = erow[d] + ent * ent_w[d] + ent_b[d];
    }
}

// ---------------------------------------------------------------------------
// Kernel 2: LayerNorm (fp32 in, bf16 out). One wave per row, 4 rows/block.
// ---------------------------------------------------------------------------
__global__ __launch_bounds__(256)
void ln_kernel(const float* __restrict__ h,
               const float* __restrict__ scale,
               const float* __restrict__ bias,
               unsigned short* __restrict__ g)
{
    int w = threadIdx.x >> 6, lane = threadIdx.x & 63;
    int row = blockIdx.x * 4 + w;
    const float* hr = h + (size_t)row * DD + lane * 8;

    float v[8];
    *reinterpret_cast<float4*>(v)     = *reinterpret_cast<const float4*>(hr);
    *reinterpret_cast<float4*>(v + 4) = *reinterpret_cast<const float4*>(hr + 4);

    float sum = 0.f, sq = 0.f;
    #pragma unroll
    for (int i = 0; i < 8; i++) { sum += v[i]; sq += v[i] * v[i]; }
    #pragma unroll
    for (int off = 32; off > 0; off >>= 1) {
        sum += __shfl_xor(sum, off);
        sq  += __shfl_xor(sq, off);
    }
    float mu = sum * (1.f / DD);
    float var = sq * (1.f / DD) - mu * mu;
    float rstd = rsqrtf(var + 1e-5f);

    float s[8], bi[8];
    *reinterpret_cast<float4*>(s)      = *reinterpret_cast<const float4*>(scale + lane * 8);
    *reinterpret_cast<float4*>(s + 4)  = *reinterpret_cast<const float4*>(scale + lane * 8 + 4);
    *reinterpret_cast<float4*>(bi)     = *reinterpret_cast<const float4*>(bias + lane * 8);
    *reinterpret_cast<float4*>(bi + 4) = *reinterpret_cast<const float4*>(bias + lane * 8 + 4);

    unsigned int pk[4];
    #pragma unroll
    for (int i = 0; i < 4; i++) {
        unsigned short lo = f2bf((v[2*i]   - mu) * rstd * s[2*i]   + bi[2*i]);
        unsigned short hi = f2bf((v[2*i+1] - mu) * rstd * s[2*i+1] + bi[2*i+1]);
        pk[i] = (unsigned)lo | ((unsigned)hi << 16);
    }
    *reinterpret_cast<uint4*>(g + (size_t)row * DD + lane * 8) =
        *reinterpret_cast<const uint4*>(pk);
}

// ---------------------------------------------------------------------------
// Kernel 3: MFMA GEMM  C[M,N] = A[M,K](bf16) * W[N,K]^T(bf16)
// 128x128 tile, BK=64, 4 waves. Double-buffered LDS + global_load_lds with
// counted s_waitcnt vmcnt(8) (T3-minimum 2-phase + T4): next tile's loads are
// in flight across the barrier while current tile computes.
// Pre-swizzled global source (seg^row) pairs with read-side XOR ((row&7)<<4).
// Epilogue: +bias(f32), gelu, +resid(f32); out f32 or bf16; n<Nn guard.
// ---------------------------------------------------------------------------
template<bool HAS_BIAS, bool GELU, bool RESID, bool OUT_BF16>
__global__ __launch_bounds__(256)
void gemm_mfma(const unsigned short* __restrict__ A,
               const unsigned short* __restrict__ W,
               const float* __restrict__ bias,
               const float* __restrict__ resid,
               void* __restrict__ Cv,
               int Nn, int Kk)
{
    __shared__ unsigned short As[2][128 * 64];
    __shared__ unsigned short Bs[2][128 * 64];

    int t = threadIdx.x;
    int w = t >> 6, lane = t & 63;
    int wr = w >> 1, wc = w & 1;
    int l15 = lane & 15, l4 = lane >> 4;
    int m0 = blockIdx.y * 128, n0 = blockIdx.x * 128;

    int lrow = lane >> 3;              // 0..7 : row within the wave's 8-row slab
    int segp = (lane & 7) ^ lrow;      // pre-swizzled 16B-segment for global fetch

    float4v acc[4][4];
    #pragma unroll
    for (int i = 0; i < 4; i++)
        #pragma unroll
        for (int j = 0; j < 4; j++)
            acc[i][j] = (float4v){0.f, 0.f, 0.f, 0.f};

    #define STAGE(buf, k0) do {                                                   \
        _Pragma("unroll")                                                         \
        for (int i_ = 0; i_ < 4; i_++) {                                          \
            int r_ = i_ * 32 + w * 8 + lrow;                                      \
            __builtin_amdgcn_global_load_lds(                                     \
                (glb_u32*)(A + (size_t)(m0 + r_) * Kk + (k0) + segp * 8),         \
                (lds_u32*)(As[buf] + i_ * 2048 + w * 512), 16, 0, 0);             \
            __builtin_amdgcn_global_load_lds(                                     \
                (glb_u32*)(W + (size_t)(n0 + r_) * Kk + (k0) + segp * 8),         \
                (lds_u32*)(Bs[buf] + i_ * 2048 + w * 512), 16, 0, 0);             \
        } } while (0)

    int nk = Kk >> 6;
    STAGE(0, 0);
    for (int kt = 0; kt < nk; kt++) {
        int cur = kt & 1;
        if (kt + 1 < nk) {
            STAGE(cur ^ 1, (kt + 1) << 6);
            __builtin_amdgcn_sched_barrier(0);
            asm volatile("s_waitcnt vmcnt(8)");   // wait only for buf[cur]'s 8 loads
            __builtin_amdgcn_sched_barrier(0);
        } else {
            __builtin_amdgcn_sched_barrier(0);
            asm volatile("s_waitcnt vmcnt(0)");
            __builtin_amdgcn_sched_barrier(0);
        }
        __builtin_amdgcn_s_barrier();

        const char* asb = (const char*)As[cur];
        const char* bsb = (const char*)Bs[cur];
        #pragma unroll
        for (int kc = 0; kc < 2; kc++) {
            short8v af[4], bfr[4];
            #pragma unroll
            for (int mf = 0; mf < 4; mf++) {
                int row = wr * 64 + mf * 16 + l15;
                int off = (row * 128 + kc * 64 + l4 * 16) ^ ((row & 7) << 4);
                af[mf] = *reinterpret_cast<const short8v*>(asb + off);
            }
            #pragma unroll
            for (int nf = 0; nf < 4; nf++) {
                int row = wc * 64 + nf * 16 + l15;
                int off = (row * 128 + kc * 64 + l4 * 16) ^ ((row & 7) << 4);
                bfr[nf] = *reinterpret_cast<const short8v*>(bsb + off);
            }
            #pragma unroll
            for (int mf = 0; mf < 4; mf++)
                #pragma unroll
                for (int nf = 0; nf < 4; nf++)
                    acc[mf][nf] = __builtin_amdgcn_mfma_f32_16x16x32_bf16(
                        af[mf], bfr[nf], acc[mf][nf], 0, 0, 0);
        }
        __builtin_amdgcn_s_barrier();
    }
    #undef STAGE

    #pragma unroll
    for (int mf = 0; mf < 4; mf++)
        #pragma unroll
        for (int nf = 0; nf < 4; nf++)
            #pragma unroll
            for (int r = 0; r < 4; r++) {
                int m = m0 + wr * 64 + mf * 16 + l4 * 4 + r;
                int n = n0 + wc * 64 + nf * 16 + l15;
                if (n < Nn) {
                    float v = acc[mf][nf][r];
                    if (HAS_BIAS) v += bias[n];
                    if (GELU)     v = 0.5f * v * (1.f + erff(v * 0.70710678118654752f));
                    if (RESID)    v += resid[(size_t)m * Nn + n];
                    if (OUT_BF16) ((unsigned short*)Cv)[(size_t)m * Nn + n] = f2bf(v);
                    else          ((float*)Cv)[(size_t)m * Nn + n] = v;
                }
            }
}

// ---------------------------------------------------------------------------
// Kernel 4: MFMA flash attention (bf16 qkv in, bf16 o out)
// grid (L/64, H, B); 256 threads = 4 waves x 16 q-rows; KB=64 key tiles.
// Swapped QK^T (S^T = mfma(K,Q)); P packed via v_cvt_pk_bf16_f32;
// defer-max rescale (THR=8, T13); per-lane partial l reduced at epilogue;
// setprio(1) around MFMA clusters (T5).
// ---------------------------------------------------------------------------
__global__ __launch_bounds__(256)
void attn_mfma(const unsigned short* __restrict__ qkv, unsigned short* __restrict__ o)
{
    __shared__ unsigned short Kl[64 * 64];     // [key][d] swizzled
    __shared__ unsigned short Vt[64 * 72];     // [d][key], stride 72 shorts, swizzled
    __shared__ unsigned short Pl[4 * 16 * 64]; // per-wave [q][key] swizzled
    __shared__ float Scl[4][16];               // per-wave per-q broadcast slot

    int t = threadIdx.x, w = t >> 6, lane = t & 63;
    int l15 = lane & 15, l4 = lane >> 4;
    int qt = blockIdx.x, hh = blockIdx.y, b = blockIdx.z;
    int q0 = qt * 64 + w * 16;
    const int RS = 3 * DD; // 1536

    // Q fragments (B-operand of swapped QK^T)
    short8v qf[2];
    #pragma unroll
    for (int dh = 0; dh < 2; dh++) {
        size_t addr = (size_t)(b * LL + q0 + l15) * RS + hh * HDIM + dh * 32 + l4 * 8;
        qf[dh] = *reinterpret_cast<const short8v*>(qkv + addr);
    }

    float4v o_acc[4];
    #pragma unroll
    for (int dt = 0; dt < 4; dt++) o_acc[dt] = (float4v){0.f, 0.f, 0.f, 0.f};
    float m_run = -1e30f, l_run = 0.f;   // per-lane; l_run = partial over own 16 keys

    char* pbase = (char*)Pl + w * 2048;

    for (int kb = 0; kb < LL / 64; kb++) {
        // global loads (issue early, write after barrier)
        short8v krg[2], vrg[2];
        #pragma unroll
        for (int i = 0; i < 2; i++) {
            int c = t + i * 256;
            int row = c >> 3, seg = c & 7;
            size_t ga = (size_t)(b * LL + kb * 64 + row) * RS + hh * HDIM + seg * 8;
            krg[i] = *reinterpret_cast<const short8v*>(qkv + ga + DD);
            vrg[i] = *reinterpret_cast<const short8v*>(qkv + ga + 2 * DD);
        }
        __syncthreads();   // previous tile's compute done
        #pragma unroll
        for (int i = 0; i < 2; i++) {
            int c = t + i * 256;
            int row = c >> 3, seg = c & 7;
            int koff = (row * 128 + seg * 16) ^ ((row & 7) << 4);
            *reinterpret_cast<short8v*>((char*)Kl + koff) = krg[i];
            #pragma unroll
            for (int e = 0; e < 8; e++) {
                int d = seg * 8 + e;                 // (d>>3)&7 == seg
                int voff = (d * 144 + row * 2) ^ (seg << 4);
                *reinterpret_cast<unsigned short*>((char*)Vt + voff) =
                    (unsigned short)vrg[i][e];
            }
        }
        __syncthreads();

        // S^T = K Q^T : lane holds keys {nt*16 + l4*4 + r} for q = l15
        float4v s_acc[4];
        __builtin_amdgcn_s_setprio(1);
        #pragma unroll
        for (int nt = 0; nt < 4; nt++) {
            s_acc[nt] = (float4v){0.f, 0.f, 0.f, 0.f};
            #pragma unroll
            for (int dh = 0; dh < 2; dh++) {
                int row = nt * 16 + l15;
                int off = (row * 128 + dh * 64 + l4 * 16) ^ ((row & 7) << 4);
                short8v kf = *reinterpret_cast<const short8v*>((const char*)Kl + off);
                s_acc[nt] = __builtin_amdgcn_mfma_f32_16x16x32_bf16(kf, qf[dh], s_acc[nt], 0, 0, 0);
            }
        }
        __builtin_amdgcn_s_setprio(0);

        // tile max (scaled), reduced across the 4 l4-copies of each q
        float mm = -1e30f;
        #pragma unroll
        for (int nt = 0; nt < 4; nt++)
            #pragma unroll
            for (int r = 0; r < 4; r++)
                mm = fmaxf(mm, s_acc[nt][r]);
        mm *= 0.125f;
        mm = fmaxf(mm, __shfl_xor(mm, 16));
        mm = fmaxf(mm, __shfl_xor(mm, 32));

        // defer-max: rescale only when max grew by > 8 (always on first tile)
        if (!__all(mm <= m_run + 8.f)) {
            float mnew = fmaxf(m_run, mm);
            float sc = __expf(m_run - mnew);
            m_run = mnew;
            l_run *= sc;
            if (l4 == 0) Scl[w][l15] = sc;
            float4 scv = *reinterpret_cast<const float4*>(&Scl[w][l4 * 4]);
            #pragma unroll
            for (int dt = 0; dt < 4; dt++) {
                o_acc[dt][0] *= scv.x; o_acc[dt][1] *= scv.y;
                o_acc[dt][2] *= scv.z; o_acc[dt][3] *= scv.w;
            }
        }

        // P = exp(S - m_run), packed to bf16 via cvt_pk; per-lane partial sum
        float ps = 0.f;
        #pragma unroll
        for (int nt = 0; nt < 4; nt++) {
            float p0 = __expf(fmaf(s_acc[nt][0], 0.125f, -m_run));
            float p1 = __expf(fmaf(s_acc[nt][1], 0.125f, -m_run));
            float p2 = __expf(fmaf(s_acc[nt][2], 0.125f, -m_run));
            float p3 = __expf(fmaf(s_acc[nt][3], 0.125f, -m_run));
            ps += (p0 + p1) + (p2 + p3);
            unsigned int pk0, pk1;
            asm("v_cvt_pk_bf16_f32 %0, %1, %2" : "=v"(pk0) : "v"(p0), "v"(p1));
            asm("v_cvt_pk_bf16_f32 %0, %1, %2" : "=v"(pk1) : "v"(p2), "v"(p3));
            uint2 pk; pk.x = pk0; pk.y = pk1;
            int off = (l15 * 128 + nt * 32 + l4 * 8) ^ ((l15 & 7) << 4);
            *reinterpret_cast<uint2*>(pbase + off) = pk;
        }
        l_run += ps;

        // O += P V
        __builtin_amdgcn_s_setprio(1);
        #pragma unroll
        for (int kc = 0; kc < 2; kc++) {
            int poff = (l15 * 128 + kc * 64 + l4 * 16) ^ ((l15 & 7) << 4);
            short8v pf = *reinterpret_cast<const short8v*>(pbase + poff);
            #pragma unroll
            for (int dt = 0; dt < 4; dt++) {
                int d = dt * 16 + l15;
                int voff = (d * 144 + kc * 64 + l4 * 16) ^ (((d >> 3) & 7) << 4);
                short8v vf = *reinterpret_cast<const short8v*>((const char*)Vt + voff);
                o_acc[dt] = __builtin_amdgcn_mfma_f32_16x16x32_bf16(pf, vf, o_acc[dt], 0, 0, 0);
            }
        }
        __builtin_amdgcn_s_setprio(0);
    }

    // epilogue: reduce l across the 4 copies, broadcast 1/l into o_acc domain
    float lt = l_run;
    lt += __shfl_xor(lt, 16);
    lt += __shfl_xor(lt, 32);
    if (l4 == 0) Scl[w][l15] = 1.f / lt;
    float4 iv = *reinterpret_cast<const float4*>(&Scl[w][l4 * 4]);
    float invs[4] = {iv.x, iv.y, iv.z, iv.w};
    #pragma unroll
    for (int r = 0; r < 4; r++) {
        int qg = q0 + l4 * 4 + r;
        #pragma unroll
        for (int dt = 0; dt < 4; dt++) {
            o[(size_t)(b * LL + qg) * DD + hh * HDIM + dt * 16 + l15] =
                f2bf(o_acc[dt][r] * invs[r]);
        }
    }
}

// ---------------------------------------------------------------------------
// Driver
// ---------------------------------------------------------------------------
extern "C" void kernel_launch(void* const* d_in, const int* in_sizes, int n_in,
                              void* d_out, int out_size, void* d_ws, size_t ws_size,
                              hipStream_t stream)
{
    const float* emb    = (const float*)d_in[0];
    const float* ent_w  = (const float*)d_in[1];
    const float* ent_b  = (const float*)d_in[2];
    const float* qkv_w  = (const float*)d_in[3];
    const float* qkv_b  = (const float*)d_in[4];
    const float* ao_w   = (const float*)d_in[5];
    const float* ao_b   = (const float*)d_in[6];
    const float* ln1_s  = (const float*)d_in[7];
    const float* ln1_b  = (const float*)d_in[8];
    const float* ln2_s  = (const float*)d_in[9];
    const float* ln2_b  = (const float*)d_in[10];
    const float* ff1_w  = (const float*)d_in[11];
    const float* ff1_b  = (const float*)d_in[12];
    const float* ff2_w  = (const float*)d_in[13];
    const float* ff2_b  = (const float*)d_in[14];
    const float* out_w  = (const float*)d_in[15];
    const int*   x      = (const int*)d_in[16];
    // d_in[17] = patch_lengths : dead code in the reference

    float* out = (float*)d_out;

    const int NQW = NLAYER * 3 * DD * DD;
    const int NAW = NLAYER * DD * DD;
    const int NF1 = NLAYER * 4 * DD * DD;
    const int NF2 = NLAYER * DD * 4 * DD;

    char* p = (char*)d_ws;
    unsigned short* wq  = (unsigned short*)p; p += (size_t)NQW * 2;
    unsigned short* wa  = (unsigned short*)p; p += (size_t)NAW * 2;
    unsigned short* w1  = (unsigned short*)p; p += (size_t)NF1 * 2;
    unsigned short* w2  = (unsigned short*)p; p += (size_t)NF2 * 2;
    unsigned short* wob = (unsigned short*)p; p += (size_t)VPAD * DD * 2;
    float*          h   = (float*)p;          p += (size_t)MM * DD * 4;
    unsigned short* hb  = (unsigned short*)p; p += (size_t)MM * DD * 2;
    unsigned short* gb  = (unsigned short*)p; p += (size_t)MM * DD * 2;
    unsigned short* ob  = (unsigned short*)p; p += (size_t)MM * DD * 2;
    unsigned short* bb  = (unsigned short*)p; p += (size_t)MM * 4 * DD * 2; // qkv / ffn

    dim3 blk(256);

    cvt_kernel<<<NQW / 1024, blk, 0, stream>>>(qkv_w, wq, NQW);
    cvt_kernel<<<NAW / 1024, blk, 0, stream>>>(ao_w,  wa, NAW);
    cvt_kernel<<<NF1 / 1024, blk, 0, stream>>>(ff1_w, w1, NF1);
    cvt_kernel<<<NF2 / 1024, blk, 0, stream>>>(ff2_w, w2, NF2);
    cvt_pad_kernel<<<(VPAD * DD) / 256, blk, 0, stream>>>(out_w, wob);

    embed_ent_kernel<<<MM, blk, 0, stream>>>(x, emb, ent_w, ent_b, h);

    for (int layer = 0; layer < NLAYER; layer++) {
        const unsigned short* qw = wq + (size_t)layer * 3 * DD * DD;
        const unsigned short* aw = wa + (size_t)layer * DD * DD;
        const unsigned short* f1 = w1 + (size_t)layer * 4 * DD * DD;
        const unsigned short* f2 = w2 + (size_t)layer * DD * 4 * DD;
        const float* qb  = qkv_b + (size_t)layer * 3 * DD;
        const float* ab  = ao_b  + (size_t)layer * DD;
        const float* l1s = ln1_s + (size_t)layer * DD;
        const float* l1b = ln1_b + (size_t)layer * DD;
        const float* l2s = ln2_s + (size_t)layer * DD;
        const float* l2b = ln2_b + (size_t)layer * DD;
        const float* f1b = ff1_b + (size_t)layer * 4 * DD;
        const float* f2b = ff2_b + (size_t)layer * DD;

        // LN1: h -> gb (bf16)
        ln_kernel<<<MM / 4, blk, 0, stream>>>(h, l1s, l1b, gb);

        // qkv = gb @ qw^T + qb -> bb (bf16) [MM,1536]
        {
            dim3 grid((3 * DD) / 128, MM / 128);
            gemm_mfma<true, false, false, true><<<grid, blk, 0, stream>>>(
                gb, qw, qb, nullptr, bb, 3 * DD, DD);
        }

        // attention: bb -> ob (bf16)
        {
            dim3 grid(LL / 64, HH, BB);
            attn_mfma<<<grid, blk, 0, stream>>>(bb, ob);
        }

        // h = h + ob @ aw^T + ab  (f32 out)
        {
            dim3 grid(DD / 128, MM / 128);
            gemm_mfma<true, false, true, false><<<grid, blk, 0, stream>>>(
                ob, aw, ab, h, h, DD, DD);
        }

        // LN2: h -> gb
        ln_kernel<<<MM / 4, blk, 0, stream>>>(h, l2s, l2b, gb);

        // ffn1: bb = gelu(gb @ f1^T + f1b) (bf16) [MM,2048]
        {
            dim3 grid((4 * DD) / 128, MM / 128);
            gemm_mfma<true, true, false, true><<<grid, blk, 0, stream>>>(
                gb, f1, f1b, nullptr, bb, 4 * DD, DD);
        }

        // ffn2: h = h + bb @ f2^T + f2b  (f32 out)
        {
            dim3 grid(DD / 128, MM / 128);
            gemm_mfma<true, false, true, false><<<grid, blk, 0, stream>>>(
                bb, f2, f2b, h, h, DD, 4 * DD);
        }
    }

    // logits = h @ out_w^T [MM, 258] via MFMA on padded weight
    cvt_kernel<<<(MM * DD) / 1024, blk, 0, stream>>>(h, hb, MM * DD);
    {
        dim3 grid(VPAD / 128, MM / 128);
        gemm_mfma<false, false, false, false><<<grid, blk, 0, stream>>>(
            hb, wob, nullptr, nullptr, out, VV, DD);
    }
}

// Round 6
// 800.731 us; speedup vs baseline: 17.6837x; 1.0618x over previous
//
#include <hip/hip_runtime.h>
#include <hip/hip_bf16.h>
#include <math.h>

// Problem constants
#define BB 4
#define LL 2048
#define DD 512
#define HH 8
#define NLAYER 4
#define VV 258
#define WW 8
#define HDIM 64
#define MM (BB * LL)   // 8192 rows
#define VPAD 384       // logits weight rows padded to tile multiple

typedef __attribute__((ext_vector_type(8))) short short8v;
typedef __attribute__((ext_vector_type(4))) float float4v;

typedef __attribute__((address_space(3))) unsigned int lds_u32;
typedef const __attribute__((address_space(1))) unsigned int glb_u32;

__device__ __forceinline__ unsigned short f2bf(float x) {
    unsigned int u = __float_as_uint(x);
    unsigned int r = (u + 0x7fffu + ((u >> 16) & 1u)) >> 16;
    return (unsigned short)r;
}

__device__ __forceinline__ unsigned lds_addr(const void* p) {
    return (unsigned)(size_t)(__attribute__((address_space(3))) const void*)p;
}

// ---------------------------------------------------------------------------
// fp32 -> bf16 bulk convert, n % 4 == 0
// ---------------------------------------------------------------------------
__global__ __launch_bounds__(256)
void cvt_kernel(const float* __restrict__ in, unsigned short* __restrict__ out, int n)
{
    int i = (blockIdx.x * 256 + threadIdx.x) * 4;
    if (i < n) {
        float4 v = *reinterpret_cast<const float4*>(in + i);
        uint2 pk;
        pk.x = (unsigned)f2bf(v.x) | ((unsigned)f2bf(v.y) << 16);
        pk.y = (unsigned)f2bf(v.z) | ((unsigned)f2bf(v.w) << 16);
        *reinterpret_cast<uint2*>(out + i) = pk;
    }
}

// fp32 [VV, DD] -> bf16 [VPAD, DD], pad rows zeroed (every launch)
__global__ __launch_bounds__(256)
void cvt_pad_kernel(const float* __restrict__ in, unsigned short* __restrict__ out)
{
    int i = blockIdx.x * 256 + threadIdx.x;
    int row = i >> 9;
    out[i] = (row < VV) ? f2bf(in[i]) : (unsigned short)0;
}

// ---------------------------------------------------------------------------
// Kernel 1: token embedding + sliding-window byte-entropy feature (fp32 out)
// values >= 256 contribute nothing (reference one_hot has 256 classes).
// ---------------------------------------------------------------------------
__global__ __launch_bounds__(256)
void embed_ent_kernel(const int* __restrict__ x,
                      const float* __restrict__ emb,
                      const float* __restrict__ ent_w,
                      const float* __restrict__ ent_b,
                      float* __restrict__ h)
{
    int row = blockIdx.x;            // 0..MM-1
    int b = row / LL, l = row % LL;

    float ent = 0.f;
    if (l <= LL - WW) {
        int win[WW];
        #pragma unroll
        for (int i = 0; i < WW; i++) win[i] = x[b * LL + l + i];
        float s = 0.f;
        #pragma unroll
        for (int i = 0; i < WW; i++) {
            if (win[i] < 256) {
                int c = 0;
                #pragma unroll
                for (int j = 0; j < WW; j++) c += (win[j] == win[i]) ? 1 : 0;
                s += log2f((float)c * 0.125f + 1e-10f);
            }
        }
        ent = -s * 0.125f;
    }

    int tok = x[b * LL + l];
    const float* erow = emb + (size_t)tok * DD;
    float* hrow = h + (size_t)row * DD;
    for (int d = threadIdx.x; d < DD; d += blockDim.x) {
        hrow[d] = erow[d] + ent * ent_w[d] + ent_b[d];
    }
}

// ---------------------------------------------------------------------------
// Kernel 2: LayerNorm (fp32 in, bf16 out). One wave per row, 4 rows/block.
// ---------------------------------------------------------------------------
__global__ __launch_bounds__(256)
void ln_kernel(const float* __restrict__ h,
               const float* __restrict__ scale,
               const float* __restrict__ bias,
               unsigned short* __restrict__ g)
{
    int w = threadIdx.x >> 6, lane = threadIdx.x & 63;
    int row = blockIdx.x * 4 + w;
    const float* hr = h + (size_t)row * DD + lane * 8;

    float v[8];
    *reinterpret_cast<float4*>(v)     = *reinterpret_cast<const float4*>(hr);
    *reinterpret_cast<float4*>(v + 4) = *reinterpret_cast<const float4*>(hr + 4);

    float sum = 0.f, sq = 0.f;
    #pragma unroll
    for (int i = 0; i < 8; i++) { sum += v[i]; sq += v[i] * v[i]; }
    #pragma unroll
    for (int off = 32; off > 0; off >>= 1) {
        sum += __shfl_xor(sum, off);
        sq  += __shfl_xor(sq, off);
    }
    float mu = sum * (1.f / DD);
    float var = sq * (1.f / DD) - mu * mu;
    float rstd = rsqrtf(var + 1e-5f);

    float s[8], bi[8];
    *reinterpret_cast<float4*>(s)      = *reinterpret_cast<const float4*>(scale + lane * 8);
    *reinterpret_cast<float4*>(s + 4)  = *reinterpret_cast<const float4*>(scale + lane * 8 + 4);
    *reinterpret_cast<float4*>(bi)     = *reinterpret_cast<const float4*>(bias + lane * 8);
    *reinterpret_cast<float4*>(bi + 4) = *reinterpret_cast<const float4*>(bias + lane * 8 + 4);

    unsigned int pk[4];
    #pragma unroll
    for (int i = 0; i < 4; i++) {
        unsigned short lo = f2bf((v[2*i]   - mu) * rstd * s[2*i]   + bi[2*i]);
        unsigned short hi = f2bf((v[2*i+1] - mu) * rstd * s[2*i+1] + bi[2*i+1]);
        pk[i] = (unsigned)lo | ((unsigned)hi << 16);
    }
    *reinterpret_cast<uint4*>(g + (size_t)row * DD + lane * 8) =
        *reinterpret_cast<const uint4*>(pk);
}

// ---------------------------------------------------------------------------
// Kernel 3: MFMA GEMM  C[M,N] = A[M,K](bf16) * W[N,K]^T(bf16)
// 128x128 tile, BK=64, 4 waves. Double-buffered LDS + global_load_lds with
// counted s_waitcnt vmcnt(8). Pre-swizzled global source (seg^row) pairs with
// read-side XOR ((row&7)<<4). Epilogue: +bias, gelu, +resid; f32/bf16 out.
// ---------------------------------------------------------------------------
template<bool HAS_BIAS, bool GELU, bool RESID, bool OUT_BF16>
__global__ __launch_bounds__(256)
void gemm_mfma(const unsigned short* __restrict__ A,
               const unsigned short* __restrict__ W,
               const float* __restrict__ bias,
               const float* __restrict__ resid,
               void* __restrict__ Cv,
               int Nn, int Kk)
{
    __shared__ unsigned short As[2][128 * 64];
    __shared__ unsigned short Bs[2][128 * 64];

    int t = threadIdx.x;
    int w = t >> 6, lane = t & 63;
    int wr = w >> 1, wc = w & 1;
    int l15 = lane & 15, l4 = lane >> 4;
    int m0 = blockIdx.y * 128, n0 = blockIdx.x * 128;

    int lrow = lane >> 3;              // 0..7 : row within the wave's 8-row slab
    int segp = (lane & 7) ^ lrow;      // pre-swizzled 16B-segment for global fetch

    float4v acc[4][4];
    #pragma unroll
    for (int i = 0; i < 4; i++)
        #pragma unroll
        for (int j = 0; j < 4; j++)
            acc[i][j] = (float4v){0.f, 0.f, 0.f, 0.f};

    #define STAGE(buf, k0) do {                                                   \
        _Pragma("unroll")                                                         \
        for (int i_ = 0; i_ < 4; i_++) {                                          \
            int r_ = i_ * 32 + w * 8 + lrow;                                      \
            __builtin_amdgcn_global_load_lds(                                     \
                (glb_u32*)(A + (size_t)(m0 + r_) * Kk + (k0) + segp * 8),         \
                (lds_u32*)(As[buf] + i_ * 2048 + w * 512), 16, 0, 0);             \
            __builtin_amdgcn_global_load_lds(                                     \
                (glb_u32*)(W + (size_t)(n0 + r_) * Kk + (k0) + segp * 8),         \
                (lds_u32*)(Bs[buf] + i_ * 2048 + w * 512), 16, 0, 0);             \
        } } while (0)

    int nk = Kk >> 6;
    STAGE(0, 0);
    for (int kt = 0; kt < nk; kt++) {
        int cur = kt & 1;
        if (kt + 1 < nk) {
            STAGE(cur ^ 1, (kt + 1) << 6);
            __builtin_amdgcn_sched_barrier(0);
            asm volatile("s_waitcnt vmcnt(8)");   // wait only for buf[cur]'s 8 loads
            __builtin_amdgcn_sched_barrier(0);
        } else {
            __builtin_amdgcn_sched_barrier(0);
            asm volatile("s_waitcnt vmcnt(0)");
            __builtin_amdgcn_sched_barrier(0);
        }
        __builtin_amdgcn_s_barrier();

        const char* asb = (const char*)As[cur];
        const char* bsb = (const char*)Bs[cur];
        #pragma unroll
        for (int kc = 0; kc < 2; kc++) {
            short8v af[4], bfr[4];
            #pragma unroll
            for (int mf = 0; mf < 4; mf++) {
                int row = wr * 64 + mf * 16 + l15;
                int off = (row * 128 + kc * 64 + l4 * 16) ^ ((row & 7) << 4);
                af[mf] = *reinterpret_cast<const short8v*>(asb + off);
            }
            #pragma unroll
            for (int nf = 0; nf < 4; nf++) {
                int row = wc * 64 + nf * 16 + l15;
                int off = (row * 128 + kc * 64 + l4 * 16) ^ ((row & 7) << 4);
                bfr[nf] = *reinterpret_cast<const short8v*>(bsb + off);
            }
            #pragma unroll
            for (int mf = 0; mf < 4; mf++)
                #pragma unroll
                for (int nf = 0; nf < 4; nf++)
                    acc[mf][nf] = __builtin_amdgcn_mfma_f32_16x16x32_bf16(
                        af[mf], bfr[nf], acc[mf][nf], 0, 0, 0);
        }
        __builtin_amdgcn_s_barrier();
    }
    #undef STAGE

    #pragma unroll
    for (int mf = 0; mf < 4; mf++)
        #pragma unroll
        for (int nf = 0; nf < 4; nf++)
            #pragma unroll
            for (int r = 0; r < 4; r++) {
                int m = m0 + wr * 64 + mf * 16 + l4 * 4 + r;
                int n = n0 + wc * 64 + nf * 16 + l15;
                if (n < Nn) {
                    float v = acc[mf][nf][r];
                    if (HAS_BIAS) v += bias[n];
                    if (GELU)     v = 0.5f * v * (1.f + erff(v * 0.70710678118654752f));
                    if (RESID)    v += resid[(size_t)m * Nn + n];
                    if (OUT_BF16) ((unsigned short*)Cv)[(size_t)m * Nn + n] = f2bf(v);
                    else          ((float*)Cv)[(size_t)m * Nn + n] = v;
                }
            }
}

// ---------------------------------------------------------------------------
// Kernel 4: MFMA flash attention (bf16 qkv in, bf16 o out)
// 512 blocks (flattened 16 qtile x 8 head x 4 batch, XCD-swizzled);
// 512 threads = 8 waves x 16 q-rows; KB=64 key tiles.
// Swapped QK^T (S^T = mfma(K,Q)); K swizzled ((row&7)<<4).
// V staged in subtiled layout [key/4][d/16][4key][16d] with one 16-B vector
// write per thread (conflict-free); PV B-frags gathered by ds_read_b64_tr_b16
// (2 per (kc,dt), conflict-free: each 16-lane group reads a 128B run).
// ---------------------------------------------------------------------------
__global__ __launch_bounds__(512, 4)
void attn_mfma(const unsigned short* __restrict__ qkv, unsigned short* __restrict__ o)
{
    __shared__ unsigned short Kl[64 * 64];     // [key][d] swizzled, 8 KB
    __shared__ unsigned short Vs[64 * 64];     // subtiled, 8 KB
    __shared__ unsigned short Pl[8 * 16 * 64]; // per-wave [q][key] swizzled, 16 KB
    __shared__ float Scl[8][16];               // per-wave per-q broadcast slot

    int t = threadIdx.x, w = t >> 6, lane = t & 63;
    int l15 = lane & 15, l4 = lane >> 4;

    // XCD-swizzled block decode (512 = 8 XCD * 64)
    int flat = blockIdx.x;
    int swz = (flat & 7) * 64 + (flat >> 3);
    int qt = swz & 15, hh = (swz >> 4) & 7, b = swz >> 7;

    int q0 = qt * 128 + w * 16;
    const int RS = 3 * DD; // 1536

    // Q fragments (B-operand of swapped QK^T)
    short8v qf[2];
    #pragma unroll
    for (int dh = 0; dh < 2; dh++) {
        size_t addr = (size_t)(b * LL + q0 + l15) * RS + hh * HDIM + dh * 32 + l4 * 8;
        qf[dh] = *reinterpret_cast<const short8v*>(qkv + addr);
    }

    float4v o_acc[4];
    #pragma unroll
    for (int dt = 0; dt < 4; dt++) o_acc[dt] = (float4v){0.f, 0.f, 0.f, 0.f};
    float m_run = -1e30f, l_run = 0.f;   // per-lane; l partial over own keys

    char* pbase = (char*)Pl + w * 2048;

    // staging coords: K natural; V permuted so the subtile write is linear
    int krow = t >> 3, kseg = t & 7;
    int vrow = ((t >> 5) << 2) | ((t >> 1) & 3);
    int vseg = (((t >> 3) & 3) << 1) | (t & 1);

    // per-lane tr-read base (bytes within Vs)
    unsigned vbase = lds_addr(Vs) + ((lane >> 4) << 10)
                   + (((lane >> 2) & 3) << 5) + ((lane & 3) << 3);

    for (int kb = 0; kb < LL / 64; kb++) {
        // global loads (issue early, write after barrier)
        size_t gaK = (size_t)(b * LL + kb * 64 + krow) * RS + hh * HDIM + DD + kseg * 8;
        size_t gaV = (size_t)(b * LL + kb * 64 + vrow) * RS + hh * HDIM + 2 * DD + vseg * 8;
        short8v krg = *reinterpret_cast<const short8v*>(qkv + gaK);
        short8v vrg = *reinterpret_cast<const short8v*>(qkv + gaV);
        __syncthreads();   // previous tile's compute done
        {
            int koff = (krow * 128 + kseg * 16) ^ ((krow & 7) << 4);
            *reinterpret_cast<short8v*>((char*)Kl + koff) = krg;
            *reinterpret_cast<short8v*>((char*)Vs + t * 16) = vrg;
        }
        __syncthreads();

        // S^T = K Q^T : lane holds keys {nt*16 + l4*4 + r} for q = l15
        float4v s_acc[4];
        __builtin_amdgcn_s_setprio(1);
        #pragma unroll
        for (int nt = 0; nt < 4; nt++) {
            s_acc[nt] = (float4v){0.f, 0.f, 0.f, 0.f};
            #pragma unroll
            for (int dh = 0; dh < 2; dh++) {
                int row = nt * 16 + l15;
                int off = (row * 128 + dh * 64 + l4 * 16) ^ ((row & 7) << 4);
                short8v kf = *reinterpret_cast<const short8v*>((const char*)Kl + off);
                s_acc[nt] = __builtin_amdgcn_mfma_f32_16x16x32_bf16(kf, qf[dh], s_acc[nt], 0, 0, 0);
            }
        }
        __builtin_amdgcn_s_setprio(0);

        // tile max (scaled), reduced across the 4 l4-copies of each q
        float mm = -1e30f;
        #pragma unroll
        for (int nt = 0; nt < 4; nt++)
            #pragma unroll
            for (int r = 0; r < 4; r++)
                mm = fmaxf(mm, s_acc[nt][r]);
        mm *= 0.125f;
        mm = fmaxf(mm, __shfl_xor(mm, 16));
        mm = fmaxf(mm, __shfl_xor(mm, 32));

        // defer-max: rescale only when max grew by > 8 (always on first tile)
        if (!__all(mm <= m_run + 8.f)) {
            float mnew = fmaxf(m_run, mm);
            float sc = __expf(m_run - mnew);
            m_run = mnew;
            l_run *= sc;
            if (l4 == 0) Scl[w][l15] = sc;
            float4 scv = *reinterpret_cast<const float4*>(&Scl[w][l4 * 4]);
            #pragma unroll
            for (int dt = 0; dt < 4; dt++) {
                o_acc[dt][0] *= scv.x; o_acc[dt][1] *= scv.y;
                o_acc[dt][2] *= scv.z; o_acc[dt][3] *= scv.w;
            }
        }

        // P = exp(S - m_run), packed to bf16 via cvt_pk; per-lane partial sum
        float ps = 0.f;
        #pragma unroll
        for (int nt = 0; nt < 4; nt++) {
            float p0 = __expf(fmaf(s_acc[nt][0], 0.125f, -m_run));
            float p1 = __expf(fmaf(s_acc[nt][1], 0.125f, -m_run));
            float p2 = __expf(fmaf(s_acc[nt][2], 0.125f, -m_run));
            float p3 = __expf(fmaf(s_acc[nt][3], 0.125f, -m_run));
            ps += (p0 + p1) + (p2 + p3);
            unsigned int pk0, pk1;
            asm("v_cvt_pk_bf16_f32 %0, %1, %2" : "=v"(pk0) : "v"(p0), "v"(p1));
            asm("v_cvt_pk_bf16_f32 %0, %1, %2" : "=v"(pk1) : "v"(p2), "v"(p3));
            uint2 pk; pk.x = pk0; pk.y = pk1;
            int off = (l15 * 128 + nt * 32 + l4 * 8) ^ ((l15 & 7) << 4);
            *reinterpret_cast<uint2*>(pbase + off) = pk;
        }
        l_run += ps;

        // O += P V : A-frag = P (wave-private LDS); B-frag via hw transpose read
        #pragma unroll
        for (int kc = 0; kc < 2; kc++) {
            int poff = (l15 * 128 + kc * 64 + l4 * 16) ^ ((l15 & 7) << 4);
            short8v pf = *reinterpret_cast<const short8v*>(pbase + poff);
            unsigned long long tr0, tr1, tr2, tr3, tr4, tr5, tr6, tr7;
            unsigned ab = vbase + kc * 4096;
            asm volatile("ds_read_b64_tr_b16 %0, %1" : "=v"(tr0) : "v"(ab));
            asm volatile("ds_read_b64_tr_b16 %0, %1" : "=v"(tr1) : "v"(ab + 512));
            asm volatile("ds_read_b64_tr_b16 %0, %1" : "=v"(tr2) : "v"(ab + 128));
            asm volatile("ds_read_b64_tr_b16 %0, %1" : "=v"(tr3) : "v"(ab + 640));
            asm volatile("ds_read_b64_tr_b16 %0, %1" : "=v"(tr4) : "v"(ab + 256));
            asm volatile("ds_read_b64_tr_b16 %0, %1" : "=v"(tr5) : "v"(ab + 768));
            asm volatile("ds_read_b64_tr_b16 %0, %1" : "=v"(tr6) : "v"(ab + 384));
            asm volatile("ds_read_b64_tr_b16 %0, %1" : "=v"(tr7) : "v"(ab + 896));
            asm volatile("s_waitcnt lgkmcnt(0)");
            __builtin_amdgcn_sched_barrier(0);
            __builtin_amdgcn_s_setprio(1);
            union { unsigned long long q[2]; short8v v; } u0, u1, u2, u3;
            u0.q[0] = tr0; u0.q[1] = tr1;
            u1.q[0] = tr2; u1.q[1] = tr3;
            u2.q[0] = tr4; u2.q[1] = tr5;
            u3.q[0] = tr6; u3.q[1] = tr7;
            o_acc[0] = __builtin_amdgcn_mfma_f32_16x16x32_bf16(pf, u0.v, o_acc[0], 0, 0, 0);
            o_acc[1] = __builtin_amdgcn_mfma_f32_16x16x32_bf16(pf, u1.v, o_acc[1], 0, 0, 0);
            o_acc[2] = __builtin_amdgcn_mfma_f32_16x16x32_bf16(pf, u2.v, o_acc[2], 0, 0, 0);
            o_acc[3] = __builtin_amdgcn_mfma_f32_16x16x32_bf16(pf, u3.v, o_acc[3], 0, 0, 0);
            __builtin_amdgcn_s_setprio(0);
        }
    }

    // epilogue: reduce l across the 4 copies, broadcast 1/l into o_acc domain
    float lt = l_run;
    lt += __shfl_xor(lt, 16);
    lt += __shfl_xor(lt, 32);
    if (l4 == 0) Scl[w][l15] = 1.f / lt;
    float4 iv = *reinterpret_cast<const float4*>(&Scl[w][l4 * 4]);
    float invs[4] = {iv.x, iv.y, iv.z, iv.w};
    #pragma unroll
    for (int r = 0; r < 4; r++) {
        int qg = q0 + l4 * 4 + r;
        #pragma unroll
        for (int dt = 0; dt < 4; dt++) {
            o[(size_t)(b * LL + qg) * DD + hh * HDIM + dt * 16 + l15] =
                f2bf(o_acc[dt][r] * invs[r]);
        }
    }
}

// ---------------------------------------------------------------------------
// Driver
// ---------------------------------------------------------------------------
extern "C" void kernel_launch(void* const* d_in, const int* in_sizes, int n_in,
                              void* d_out, int out_size, void* d_ws, size_t ws_size,
                              hipStream_t stream)
{
    const float* emb    = (const float*)d_in[0];
    const float* ent_w  = (const float*)d_in[1];
    const float* ent_b  = (const float*)d_in[2];
    const float* qkv_w  = (const float*)d_in[3];
    const float* qkv_b  = (const float*)d_in[4];
    const float* ao_w   = (const float*)d_in[5];
    const float* ao_b   = (const float*)d_in[6];
    const float* ln1_s  = (const float*)d_in[7];
    const float* ln1_b  = (const float*)d_in[8];
    const float* ln2_s  = (const float*)d_in[9];
    const float* ln2_b  = (const float*)d_in[10];
    const float* ff1_w  = (const float*)d_in[11];
    const float* ff1_b  = (const float*)d_in[12];
    const float* ff2_w  = (const float*)d_in[13];
    const float* ff2_b  = (const float*)d_in[14];
    const float* out_w  = (const float*)d_in[15];
    const int*   x      = (const int*)d_in[16];
    // d_in[17] = patch_lengths : dead code in the reference

    float* out = (float*)d_out;

    const int NQW = NLAYER * 3 * DD * DD;
    const int NAW = NLAYER * DD * DD;
    const int NF1 = NLAYER * 4 * DD * DD;
    const int NF2 = NLAYER * DD * 4 * DD;

    char* p = (char*)d_ws;
    unsigned short* wq  = (unsigned short*)p; p += (size_t)NQW * 2;
    unsigned short* wa  = (unsigned short*)p; p += (size_t)NAW * 2;
    unsigned short* w1  = (unsigned short*)p; p += (size_t)NF1 * 2;
    unsigned short* w2  = (unsigned short*)p; p += (size_t)NF2 * 2;
    unsigned short* wob = (unsigned short*)p; p += (size_t)VPAD * DD * 2;
    float*          h   = (float*)p;          p += (size_t)MM * DD * 4;
    unsigned short* hb  = (unsigned short*)p; p += (size_t)MM * DD * 2;
    unsigned short* gb  = (unsigned short*)p; p += (size_t)MM * DD * 2;
    unsigned short* ob  = (unsigned short*)p; p += (size_t)MM * DD * 2;
    unsigned short* bb  = (unsigned short*)p; p += (size_t)MM * 4 * DD * 2; // qkv / ffn

    dim3 blk(256);

    cvt_kernel<<<NQW / 1024, blk, 0, stream>>>(qkv_w, wq, NQW);
    cvt_kernel<<<NAW / 1024, blk, 0, stream>>>(ao_w,  wa, NAW);
    cvt_kernel<<<NF1 / 1024, blk, 0, stream>>>(ff1_w, w1, NF1);
    cvt_kernel<<<NF2 / 1024, blk, 0, stream>>>(ff2_w, w2, NF2);
    cvt_pad_kernel<<<(VPAD * DD) / 256, blk, 0, stream>>>(out_w, wob);

    embed_ent_kernel<<<MM, blk, 0, stream>>>(x, emb, ent_w, ent_b, h);

    for (int layer = 0; layer < NLAYER; layer++) {
        const unsigned short* qw = wq + (size_t)layer * 3 * DD * DD;
        const unsigned short* aw = wa + (size_t)layer * DD * DD;
        const unsigned short* f1 = w1 + (size_t)layer * 4 * DD * DD;
        const unsigned short* f2 = w2 + (size_t)layer * DD * 4 * DD;
        const float* qb  = qkv_b + (size_t)layer * 3 * DD;
        const float* ab  = ao_b  + (size_t)layer * DD;
        const float* l1s = ln1_s + (size_t)layer * DD;
        const float* l1b = ln1_b + (size_t)layer * DD;
        const float* l2s = ln2_s + (size_t)layer * DD;
        const float* l2b = ln2_b + (size_t)layer * DD;
        const float* f1b = ff1_b + (size_t)layer * 4 * DD;
        const float* f2b = ff2_b + (size_t)layer * DD;

        // LN1: h -> gb (bf16)
        ln_kernel<<<MM / 4, blk, 0, stream>>>(h, l1s, l1b, gb);

        // qkv = gb @ qw^T + qb -> bb (bf16) [MM,1536]
        {
            dim3 grid((3 * DD) / 128, MM / 128);
            gemm_mfma<true, false, false, true><<<grid, blk, 0, stream>>>(
                gb, qw, qb, nullptr, bb, 3 * DD, DD);
        }

        // attention: bb -> ob (bf16)
        attn_mfma<<<512, 512, 0, stream>>>(bb, ob);

        // h = h + ob @ aw^T + ab  (f32 out)
        {
            dim3 grid(DD / 128, MM / 128);
            gemm_mfma<true, false, true, false><<<grid, blk, 0, stream>>>(
                ob, aw, ab, h, h, DD, DD);
        }

        // LN2: h -> gb
        ln_kernel<<<MM / 4, blk, 0, stream>>>(h, l2s, l2b, gb);

        // ffn1: bb = gelu(gb @ f1^T + f1b) (bf16) [MM,2048]
        {
            dim3 grid((4 * DD) / 128, MM / 128);
            gemm_mfma<true, true, false, true><<<grid, blk, 0, stream>>>(
                gb, f1, f1b, nullptr, bb, 4 * DD, DD);
        }

        // ffn2: h = h + bb @ f2^T + f2b  (f32 out)
        {
            dim3 grid(DD / 128, MM / 128);
            gemm_mfma<true, false, true, false><<<grid, blk, 0, stream>>>(
                bb, f2, f2b, h, h, DD, 4 * DD);
        }
    }

    // logits = h @ out_w^T [MM, 258] via MFMA on padded weight
    cvt_kernel<<<(MM * DD) / 1024, blk, 0, stream>>>(h, hb, MM * DD);
    {
        dim3 grid(VPAD / 128, MM / 128);
        gemm_mfma<false, false, false, false><<<grid, blk, 0, stream>>>(
            hb, wob, nullptr, nullptr, out, VV, DD);
    }
}

// Round 7
// 782.177 us; speedup vs baseline: 18.1032x; 1.0237x over previous
//
#include <hip/hip_runtime.h>
#include <hip/hip_bf16.h>
#include <math.h>

// Problem constants
#define BB 4
#define LL 2048
#define DD 512
#define HH 8
#define NLAYER 4
#define VV 258
#define WW 8
#define HDIM 64
#define MM (BB * LL)   // 8192 rows
#define VPAD 384       // logits weight rows padded to tile multiple

typedef __attribute__((ext_vector_type(8))) short short8v;
typedef __attribute__((ext_vector_type(4))) float float4v;

typedef __attribute__((address_space(3))) unsigned int lds_u32;
typedef const __attribute__((address_space(1))) unsigned int glb_u32;

__device__ __forceinline__ unsigned short f2bf(float x) {
    unsigned int u = __float_as_uint(x);
    unsigned int r = (u + 0x7fffu + ((u >> 16) & 1u)) >> 16;
    return (unsigned short)r;
}

__device__ __forceinline__ unsigned lds_addr(const void* p) {
    return (unsigned)(size_t)(__attribute__((address_space(3))) const void*)p;
}

// ---------------------------------------------------------------------------
// fp32 -> bf16 bulk convert, n % 4 == 0
// ---------------------------------------------------------------------------
__global__ __launch_bounds__(256)
void cvt_kernel(const float* __restrict__ in, unsigned short* __restrict__ out, int n)
{
    int i = (blockIdx.x * 256 + threadIdx.x) * 4;
    if (i < n) {
        float4 v = *reinterpret_cast<const float4*>(in + i);
        uint2 pk;
        pk.x = (unsigned)f2bf(v.x) | ((unsigned)f2bf(v.y) << 16);
        pk.y = (unsigned)f2bf(v.z) | ((unsigned)f2bf(v.w) << 16);
        *reinterpret_cast<uint2*>(out + i) = pk;
    }
}

// fp32 [VV, DD] -> bf16 [VPAD, DD], pad rows zeroed (every launch)
__global__ __launch_bounds__(256)
void cvt_pad_kernel(const float* __restrict__ in, unsigned short* __restrict__ out)
{
    int i = blockIdx.x * 256 + threadIdx.x;
    int row = i >> 9;
    out[i] = (row < VV) ? f2bf(in[i]) : (unsigned short)0;
}

// ---------------------------------------------------------------------------
// Kernel 1: fused token embedding + entropy feature + LN1(layer 0)
// One wave per row, 4 rows/block. Writes h (f32, pre-LN) and g (bf16, LN'd).
// Entropy: window x[b,l:l+8] for l <= L-W; values >= 256 contribute nothing.
// ---------------------------------------------------------------------------
__global__ __launch_bounds__(256)
void embed_ln_kernel(const int* __restrict__ x,
                     const float* __restrict__ emb,
                     const float* __restrict__ ent_w,
                     const float* __restrict__ ent_b,
                     const float* __restrict__ ln_s,
                     const float* __restrict__ ln_b,
                     float* __restrict__ h,
                     unsigned short* __restrict__ g)
{
    int w = threadIdx.x >> 6, lane = threadIdx.x & 63;
    int row = blockIdx.x * 4 + w;
    int b = row / LL, l = row % LL;

    float ent = 0.f;
    if (l <= LL - WW) {
        int win[WW];
        #pragma unroll
        for (int i = 0; i < WW; i++) win[i] = x[b * LL + l + i];
        float s = 0.f;
        #pragma unroll
        for (int i = 0; i < WW; i++) {
            if (win[i] < 256) {
                int c = 0;
                #pragma unroll
                for (int j = 0; j < WW; j++) c += (win[j] == win[i]) ? 1 : 0;
                s += log2f((float)c * 0.125f + 1e-10f);
            }
        }
        ent = -s * 0.125f;
    }

    int tok = x[row];
    const float* erow = emb + (size_t)tok * DD + lane * 8;
    float v[8], ew[8], eb[8];
    *reinterpret_cast<float4*>(v)      = *reinterpret_cast<const float4*>(erow);
    *reinterpret_cast<float4*>(v + 4)  = *reinterpret_cast<const float4*>(erow + 4);
    *reinterpret_cast<float4*>(ew)     = *reinterpret_cast<const float4*>(ent_w + lane * 8);
    *reinterpret_cast<float4*>(ew + 4) = *reinterpret_cast<const float4*>(ent_w + lane * 8 + 4);
    *reinterpret_cast<float4*>(eb)     = *reinterpret_cast<const float4*>(ent_b + lane * 8);
    *reinterpret_cast<float4*>(eb + 4) = *reinterpret_cast<const float4*>(ent_b + lane * 8 + 4);

    float sum = 0.f, sq = 0.f;
    #pragma unroll
    for (int i = 0; i < 8; i++) {
        v[i] = v[i] + ent * ew[i] + eb[i];
        sum += v[i]; sq += v[i] * v[i];
    }
    float* hr = h + (size_t)row * DD + lane * 8;
    *reinterpret_cast<float4*>(hr)     = *reinterpret_cast<const float4*>(v);
    *reinterpret_cast<float4*>(hr + 4) = *reinterpret_cast<const float4*>(v + 4);

    #pragma unroll
    for (int off = 32; off > 0; off >>= 1) {
        sum += __shfl_xor(sum, off);
        sq  += __shfl_xor(sq, off);
    }
    float mu = sum * (1.f / DD);
    float var = sq * (1.f / DD) - mu * mu;
    float rstd = rsqrtf(var + 1e-5f);

    float s8[8], bi[8];
    *reinterpret_cast<float4*>(s8)     = *reinterpret_cast<const float4*>(ln_s + lane * 8);
    *reinterpret_cast<float4*>(s8 + 4) = *reinterpret_cast<const float4*>(ln_s + lane * 8 + 4);
    *reinterpret_cast<float4*>(bi)     = *reinterpret_cast<const float4*>(ln_b + lane * 8);
    *reinterpret_cast<float4*>(bi + 4) = *reinterpret_cast<const float4*>(ln_b + lane * 8 + 4);

    unsigned int pk[4];
    #pragma unroll
    for (int i = 0; i < 4; i++) {
        unsigned short lo = f2bf((v[2*i]   - mu) * rstd * s8[2*i]   + bi[2*i]);
        unsigned short hi = f2bf((v[2*i+1] - mu) * rstd * s8[2*i+1] + bi[2*i+1]);
        pk[i] = (unsigned)lo | ((unsigned)hi << 16);
    }
    *reinterpret_cast<uint4*>(g + (size_t)row * DD + lane * 8) =
        *reinterpret_cast<const uint4*>(pk);
}

// ---------------------------------------------------------------------------
// Kernel 2: LayerNorm (fp32 in, bf16 out). One wave per row, 4 rows/block.
// ---------------------------------------------------------------------------
__global__ __launch_bounds__(256)
void ln_kernel(const float* __restrict__ h,
               const float* __restrict__ scale,
               const float* __restrict__ bias,
               unsigned short* __restrict__ g)
{
    int w = threadIdx.x >> 6, lane = threadIdx.x & 63;
    int row = blockIdx.x * 4 + w;
    const float* hr = h + (size_t)row * DD + lane * 8;

    float v[8];
    *reinterpret_cast<float4*>(v)     = *reinterpret_cast<const float4*>(hr);
    *reinterpret_cast<float4*>(v + 4) = *reinterpret_cast<const float4*>(hr + 4);

    float sum = 0.f, sq = 0.f;
    #pragma unroll
    for (int i = 0; i < 8; i++) { sum += v[i]; sq += v[i] * v[i]; }
    #pragma unroll
    for (int off = 32; off > 0; off >>= 1) {
        sum += __shfl_xor(sum, off);
        sq  += __shfl_xor(sq, off);
    }
    float mu = sum * (1.f / DD);
    float var = sq * (1.f / DD) - mu * mu;
    float rstd = rsqrtf(var + 1e-5f);

    float s[8], bi[8];
    *reinterpret_cast<float4*>(s)      = *reinterpret_cast<const float4*>(scale + lane * 8);
    *reinterpret_cast<float4*>(s + 4)  = *reinterpret_cast<const float4*>(scale + lane * 8 + 4);
    *reinterpret_cast<float4*>(bi)     = *reinterpret_cast<const float4*>(bias + lane * 8);
    *reinterpret_cast<float4*>(bi + 4) = *reinterpret_cast<const float4*>(bias + lane * 8 + 4);

    unsigned int pk[4];
    #pragma unroll
    for (int i = 0; i < 4; i++) {
        unsigned short lo = f2bf((v[2*i]   - mu) * rstd * s[2*i]   + bi[2*i]);
        unsigned short hi = f2bf((v[2*i+1] - mu) * rstd * s[2*i+1] + bi[2*i+1]);
        pk[i] = (unsigned)lo | ((unsigned)hi << 16);
    }
    *reinterpret_cast<uint4*>(g + (size_t)row * DD + lane * 8) =
        *reinterpret_cast<const uint4*>(pk);
}

// ---------------------------------------------------------------------------
// Kernel 3: MFMA GEMM  C[M,N] = A[M,K](bf16) * W[N,K]^T(bf16)
// 128x128 tile, BK=64, 4 waves. Double-buffered LDS + global_load_lds with
// counted s_waitcnt vmcnt(8). Pre-swizzled global source (seg^row) pairs with
// read-side XOR ((row&7)<<4). Epilogue: +bias, gelu, +resid.
// OMODE: 0 = f32 out, 1 = bf16 out, 2 = f32 out + bf16 copy to Cb.
// ---------------------------------------------------------------------------
template<bool HAS_BIAS, bool GELU, bool RESID, int OMODE>
__global__ __launch_bounds__(256)
void gemm_mfma(const unsigned short* __restrict__ A,
               const unsigned short* __restrict__ W,
               const float* __restrict__ bias,
               const float* __restrict__ resid,
               void* __restrict__ Cv,
               unsigned short* __restrict__ Cb,
               int Nn, int Kk)
{
    __shared__ unsigned short As[2][128 * 64];
    __shared__ unsigned short Bs[2][128 * 64];

    int t = threadIdx.x;
    int w = t >> 6, lane = t & 63;
    int wr = w >> 1, wc = w & 1;
    int l15 = lane & 15, l4 = lane >> 4;
    int m0 = blockIdx.y * 128, n0 = blockIdx.x * 128;

    int lrow = lane >> 3;              // 0..7 : row within the wave's 8-row slab
    int segp = (lane & 7) ^ lrow;      // pre-swizzled 16B-segment for global fetch

    float4v acc[4][4];
    #pragma unroll
    for (int i = 0; i < 4; i++)
        #pragma unroll
        for (int j = 0; j < 4; j++)
            acc[i][j] = (float4v){0.f, 0.f, 0.f, 0.f};

    #define STAGE(buf, k0) do {                                                   \
        _Pragma("unroll")                                                         \
        for (int i_ = 0; i_ < 4; i_++) {                                          \
            int r_ = i_ * 32 + w * 8 + lrow;                                      \
            __builtin_amdgcn_global_load_lds(                                     \
                (glb_u32*)(A + (size_t)(m0 + r_) * Kk + (k0) + segp * 8),         \
                (lds_u32*)(As[buf] + i_ * 2048 + w * 512), 16, 0, 0);             \
            __builtin_amdgcn_global_load_lds(                                     \
                (glb_u32*)(W + (size_t)(n0 + r_) * Kk + (k0) + segp * 8),         \
                (lds_u32*)(Bs[buf] + i_ * 2048 + w * 512), 16, 0, 0);             \
        } } while (0)

    int nk = Kk >> 6;
    STAGE(0, 0);
    for (int kt = 0; kt < nk; kt++) {
        int cur = kt & 1;
        if (kt + 1 < nk) {
            STAGE(cur ^ 1, (kt + 1) << 6);
            __builtin_amdgcn_sched_barrier(0);
            asm volatile("s_waitcnt vmcnt(8)");   // wait only for buf[cur]'s 8 loads
            __builtin_amdgcn_sched_barrier(0);
        } else {
            __builtin_amdgcn_sched_barrier(0);
            asm volatile("s_waitcnt vmcnt(0)");
            __builtin_amdgcn_sched_barrier(0);
        }
        __builtin_amdgcn_s_barrier();

        const char* asb = (const char*)As[cur];
        const char* bsb = (const char*)Bs[cur];
        #pragma unroll
        for (int kc = 0; kc < 2; kc++) {
            short8v af[4], bfr[4];
            #pragma unroll
            for (int mf = 0; mf < 4; mf++) {
                int row = wr * 64 + mf * 16 + l15;
                int off = (row * 128 + kc * 64 + l4 * 16) ^ ((row & 7) << 4);
                af[mf] = *reinterpret_cast<const short8v*>(asb + off);
            }
            #pragma unroll
            for (int nf = 0; nf < 4; nf++) {
                int row = wc * 64 + nf * 16 + l15;
                int off = (row * 128 + kc * 64 + l4 * 16) ^ ((row & 7) << 4);
                bfr[nf] = *reinterpret_cast<const short8v*>(bsb + off);
            }
            #pragma unroll
            for (int mf = 0; mf < 4; mf++)
                #pragma unroll
                for (int nf = 0; nf < 4; nf++)
                    acc[mf][nf] = __builtin_amdgcn_mfma_f32_16x16x32_bf16(
                        af[mf], bfr[nf], acc[mf][nf], 0, 0, 0);
        }
        __builtin_amdgcn_s_barrier();
    }
    #undef STAGE

    #pragma unroll
    for (int mf = 0; mf < 4; mf++)
        #pragma unroll
        for (int nf = 0; nf < 4; nf++)
            #pragma unroll
            for (int r = 0; r < 4; r++) {
                int m = m0 + wr * 64 + mf * 16 + l4 * 4 + r;
                int n = n0 + wc * 64 + nf * 16 + l15;
                if (n < Nn) {
                    float v = acc[mf][nf][r];
                    if (HAS_BIAS) v += bias[n];
                    if (GELU)     v = 0.5f * v * (1.f + erff(v * 0.70710678118654752f));
                    if (RESID)    v += resid[(size_t)m * Nn + n];
                    if (OMODE == 1) {
                        ((unsigned short*)Cv)[(size_t)m * Nn + n] = f2bf(v);
                    } else {
                        ((float*)Cv)[(size_t)m * Nn + n] = v;
                        if (OMODE == 2) Cb[(size_t)m * Nn + n] = f2bf(v);
                    }
                }
            }
}

// ---------------------------------------------------------------------------
// Kernel 4: MFMA flash attention (bf16 qkv in, bf16 o out)
// 512 blocks (16 qtile x 8 head x 4 batch flattened, XCD-swizzled);
// 512 threads = 8 waves x 16 q-rows; KB=64 key tiles, K/V double-buffered:
// one barrier per tile, next tile's global loads issued before compute.
// Swapped QK^T (S^T = mfma(K,Q)); K swizzled ((row&7)<<4); V subtiled
// [key/4][d/16][4key][16d] (one 16-B write/thread), PV B-frags via
// ds_read_b64_tr_b16.
// ---------------------------------------------------------------------------
__global__ __launch_bounds__(512, 2)
void attn_mfma(const unsigned short* __restrict__ qkv, unsigned short* __restrict__ o)
{
    __shared__ unsigned short Kl[2][64 * 64];  // [key][d] swizzled, 8 KB each
    __shared__ unsigned short Vs[2][64 * 64];  // subtiled, 8 KB each
    __shared__ unsigned short Pl[8 * 16 * 64]; // per-wave [q][key] swizzled, 16 KB
    __shared__ float Scl[8][16];               // per-wave per-q broadcast slot

    int t = threadIdx.x, w = t >> 6, lane = t & 63;
    int l15 = lane & 15, l4 = lane >> 4;

    // XCD-swizzled block decode (512 = 8 XCD * 64)
    int flat = blockIdx.x;
    int swz = (flat & 7) * 64 + (flat >> 3);
    int qt = swz & 15, hh = (swz >> 4) & 7, b = swz >> 7;

    int q0 = qt * 128 + w * 16;
    const int RS = 3 * DD; // 1536

    // Q fragments (B-operand of swapped QK^T)
    short8v qf[2];
    #pragma unroll
    for (int dh = 0; dh < 2; dh++) {
        size_t addr = (size_t)(b * LL + q0 + l15) * RS + hh * HDIM + dh * 32 + l4 * 8;
        qf[dh] = *reinterpret_cast<const short8v*>(qkv + addr);
    }

    float4v o_acc[4];
    #pragma unroll
    for (int dt = 0; dt < 4; dt++) o_acc[dt] = (float4v){0.f, 0.f, 0.f, 0.f};
    float m_run = -1e30f, l_run = 0.f;   // per-lane; l partial over own keys

    char* pbase = (char*)Pl + w * 2048;

    // staging coords: K natural; V permuted so the subtile write is linear
    int krow = t >> 3, kseg = t & 7;
    int vrow = ((t >> 5) << 2) | ((t >> 1) & 3);
    int vseg = (((t >> 3) & 3) << 1) | (t & 1);
    int koff = (krow * 128 + kseg * 16) ^ ((krow & 7) << 4);
    int voff = t * 16;

    const unsigned short* kptr = qkv + (size_t)(b * LL + krow) * RS + hh * HDIM + DD + kseg * 8;
    const unsigned short* vptr = qkv + (size_t)(b * LL + vrow) * RS + hh * HDIM + 2 * DD + vseg * 8;
    const int step = 64 * RS;

    // per-lane tr-read base (bytes within one Vs buffer)
    unsigned vtrbase = lds_addr(Vs) + ((lane >> 4) << 10)
                     + (((lane >> 2) & 3) << 5) + ((lane & 3) << 3);

    // prologue: stage tile 0 into buf 0
    {
        short8v krg = *reinterpret_cast<const short8v*>(kptr); kptr += step;
        short8v vrg = *reinterpret_cast<const short8v*>(vptr); vptr += step;
        *reinterpret_cast<short8v*>((char*)Kl[0] + koff) = krg;
        *reinterpret_cast<short8v*>((char*)Vs[0] + voff) = vrg;
    }
    __syncthreads();

    for (int kb = 0; kb < LL / 64; kb++) {
        int cur = kb & 1;
        // issue next tile's global loads (latency hides under compute)
        short8v krg, vrg;
        if (kb + 1 < LL / 64) {
            krg = *reinterpret_cast<const short8v*>(kptr); kptr += step;
            vrg = *reinterpret_cast<const short8v*>(vptr); vptr += step;
        }

        const char* klc = (const char*)Kl[cur];
        unsigned vb = vtrbase + cur * 8192;

        // S^T = K Q^T : lane holds keys {nt*16 + l4*4 + r} for q = l15
        float4v s_acc[4];
        __builtin_amdgcn_s_setprio(1);
        #pragma unroll
        for (int nt = 0; nt < 4; nt++) {
            s_acc[nt] = (float4v){0.f, 0.f, 0.f, 0.f};
            #pragma unroll
            for (int dh = 0; dh < 2; dh++) {
                int row = nt * 16 + l15;
                int off = (row * 128 + dh * 64 + l4 * 16) ^ ((row & 7) << 4);
                short8v kf = *reinterpret_cast<const short8v*>(klc + off);
                s_acc[nt] = __builtin_amdgcn_mfma_f32_16x16x32_bf16(kf, qf[dh], s_acc[nt], 0, 0, 0);
            }
        }
        __builtin_amdgcn_s_setprio(0);

        // tile max (scaled), reduced across the 4 l4-copies of each q
        float mm = -1e30f;
        #pragma unroll
        for (int nt = 0; nt < 4; nt++)
            #pragma unroll
            for (int r = 0; r < 4; r++)
                mm = fmaxf(mm, s_acc[nt][r]);
        mm *= 0.125f;
        mm = fmaxf(mm, __shfl_xor(mm, 16));
        mm = fmaxf(mm, __shfl_xor(mm, 32));

        // defer-max: rescale only when max grew by > 8 (always on first tile)
        if (!__all(mm <= m_run + 8.f)) {
            float mnew = fmaxf(m_run, mm);
            float sc = __expf(m_run - mnew);
            m_run = mnew;
            l_run *= sc;
            if (l4 == 0) Scl[w][l15] = sc;
            float4 scv = *reinterpret_cast<const float4*>(&Scl[w][l4 * 4]);
            #pragma unroll
            for (int dt = 0; dt < 4; dt++) {
                o_acc[dt][0] *= scv.x; o_acc[dt][1] *= scv.y;
                o_acc[dt][2] *= scv.z; o_acc[dt][3] *= scv.w;
            }
        }

        // P = exp(S - m_run), packed to bf16 via cvt_pk; per-lane partial sum
        float ps = 0.f;
        #pragma unroll
        for (int nt = 0; nt < 4; nt++) {
            float p0 = __expf(fmaf(s_acc[nt][0], 0.125f, -m_run));
            float p1 = __expf(fmaf(s_acc[nt][1], 0.125f, -m_run));
            float p2 = __expf(fmaf(s_acc[nt][2], 0.125f, -m_run));
            float p3 = __expf(fmaf(s_acc[nt][3], 0.125f, -m_run));
            ps += (p0 + p1) + (p2 + p3);
            unsigned int pk0, pk1;
            asm("v_cvt_pk_bf16_f32 %0, %1, %2" : "=v"(pk0) : "v"(p0), "v"(p1));
            asm("v_cvt_pk_bf16_f32 %0, %1, %2" : "=v"(pk1) : "v"(p2), "v"(p3));
            uint2 pk; pk.x = pk0; pk.y = pk1;
            int off = (l15 * 128 + nt * 32 + l4 * 8) ^ ((l15 & 7) << 4);
            *reinterpret_cast<uint2*>(pbase + off) = pk;
        }
        l_run += ps;

        // O += P V : A-frag = P (wave-private LDS); B-frag via hw transpose read
        #pragma unroll
        for (int kc = 0; kc < 2; kc++) {
            int poff = (l15 * 128 + kc * 64 + l4 * 16) ^ ((l15 & 7) << 4);
            short8v pf = *reinterpret_cast<const short8v*>(pbase + poff);
            unsigned long long tr0, tr1, tr2, tr3, tr4, tr5, tr6, tr7;
            unsigned ab = vb + kc * 4096;
            asm volatile("ds_read_b64_tr_b16 %0, %1" : "=v"(tr0) : "v"(ab));
            asm volatile("ds_read_b64_tr_b16 %0, %1" : "=v"(tr1) : "v"(ab + 512));
            asm volatile("ds_read_b64_tr_b16 %0, %1" : "=v"(tr2) : "v"(ab + 128));
            asm volatile("ds_read_b64_tr_b16 %0, %1" : "=v"(tr3) : "v"(ab + 640));
            asm volatile("ds_read_b64_tr_b16 %0, %1" : "=v"(tr4) : "v"(ab + 256));
            asm volatile("ds_read_b64_tr_b16 %0, %1" : "=v"(tr5) : "v"(ab + 768));
            asm volatile("ds_read_b64_tr_b16 %0, %1" : "=v"(tr6) : "v"(ab + 384));
            asm volatile("ds_read_b64_tr_b16 %0, %1" : "=v"(tr7) : "v"(ab + 896));
            asm volatile("s_waitcnt lgkmcnt(0)");
            __builtin_amdgcn_sched_barrier(0);
            __builtin_amdgcn_s_setprio(1);
            union { unsigned long long q[2]; short8v v; } u0, u1, u2, u3;
            u0.q[0] = tr0; u0.q[1] = tr1;
            u1.q[0] = tr2; u1.q[1] = tr3;
            u2.q[0] = tr4; u2.q[1] = tr5;
            u3.q[0] = tr6; u3.q[1] = tr7;
            o_acc[0] = __builtin_amdgcn_mfma_f32_16x16x32_bf16(pf, u0.v, o_acc[0], 0, 0, 0);
            o_acc[1] = __builtin_amdgcn_mfma_f32_16x16x32_bf16(pf, u1.v, o_acc[1], 0, 0, 0);
            o_acc[2] = __builtin_amdgcn_mfma_f32_16x16x32_bf16(pf, u2.v, o_acc[2], 0, 0, 0);
            o_acc[3] = __builtin_amdgcn_mfma_f32_16x16x32_bf16(pf, u3.v, o_acc[3], 0, 0, 0);
            __builtin_amdgcn_s_setprio(0);
        }

        // stage next tile into the other buffer; one barrier per tile
        if (kb + 1 < LL / 64) {
            *reinterpret_cast<short8v*>((char*)Kl[cur ^ 1] + koff) = krg;
            *reinterpret_cast<short8v*>((char*)Vs[cur ^ 1] + voff) = vrg;
        }
        __syncthreads();
    }

    // epilogue: reduce l across the 4 copies, broadcast 1/l into o_acc domain
    float lt = l_run;
    lt += __shfl_xor(lt, 16);
    lt += __shfl_xor(lt, 32);
    if (l4 == 0) Scl[w][l15] = 1.f / lt;
    float4 iv = *reinterpret_cast<const float4*>(&Scl[w][l4 * 4]);
    float invs[4] = {iv.x, iv.y, iv.z, iv.w};
    #pragma unroll
    for (int r = 0; r < 4; r++) {
        int qg = q0 + l4 * 4 + r;
        #pragma unroll
        for (int dt = 0; dt < 4; dt++) {
            o[(size_t)(b * LL + qg) * DD + hh * HDIM + dt * 16 + l15] =
                f2bf(o_acc[dt][r] * invs[r]);
        }
    }
}

// ---------------------------------------------------------------------------
// Driver
// ---------------------------------------------------------------------------
extern "C" void kernel_launch(void* const* d_in, const int* in_sizes, int n_in,
                              void* d_out, int out_size, void* d_ws, size_t ws_size,
                              hipStream_t stream)
{
    const float* emb    = (const float*)d_in[0];
    const float* ent_w  = (const float*)d_in[1];
    const float* ent_b  = (const float*)d_in[2];
    const float* qkv_w  = (const float*)d_in[3];
    const float* qkv_b  = (const float*)d_in[4];
    const float* ao_w   = (const float*)d_in[5];
    const float* ao_b   = (const float*)d_in[6];
    const float* ln1_s  = (const float*)d_in[7];
    const float* ln1_b  = (const float*)d_in[8];
    const float* ln2_s  = (const float*)d_in[9];
    const float* ln2_b  = (const float*)d_in[10];
    const float* ff1_w  = (const float*)d_in[11];
    const float* ff1_b  = (const float*)d_in[12];
    const float* ff2_w  = (const float*)d_in[13];
    const float* ff2_b  = (const float*)d_in[14];
    const float* out_w  = (const float*)d_in[15];
    const int*   x      = (const int*)d_in[16];
    // d_in[17] = patch_lengths : dead code in the reference

    float* out = (float*)d_out;

    const int NQW = NLAYER * 3 * DD * DD;
    const int NAW = NLAYER * DD * DD;
    const int NF1 = NLAYER * 4 * DD * DD;
    const int NF2 = NLAYER * DD * 4 * DD;

    char* p = (char*)d_ws;
    unsigned short* wq  = (unsigned short*)p; p += (size_t)NQW * 2;
    unsigned short* wa  = (unsigned short*)p; p += (size_t)NAW * 2;
    unsigned short* w1  = (unsigned short*)p; p += (size_t)NF1 * 2;
    unsigned short* w2  = (unsigned short*)p; p += (size_t)NF2 * 2;
    unsigned short* wob = (unsigned short*)p; p += (size_t)VPAD * DD * 2;
    float*          h   = (float*)p;          p += (size_t)MM * DD * 4;
    unsigned short* hb  = (unsigned short*)p; p += (size_t)MM * DD * 2;
    unsigned short* gb  = (unsigned short*)p; p += (size_t)MM * DD * 2;
    unsigned short* ob  = (unsigned short*)p; p += (size_t)MM * DD * 2;
    unsigned short* bb  = (unsigned short*)p; p += (size_t)MM * 4 * DD * 2; // qkv / ffn

    dim3 blk(256);

    cvt_kernel<<<NQW / 1024, blk, 0, stream>>>(qkv_w, wq, NQW);
    cvt_kernel<<<NAW / 1024, blk, 0, stream>>>(ao_w,  wa, NAW);
    cvt_kernel<<<NF1 / 1024, blk, 0, stream>>>(ff1_w, w1, NF1);
    cvt_kernel<<<NF2 / 1024, blk, 0, stream>>>(ff2_w, w2, NF2);
    cvt_pad_kernel<<<(VPAD * DD) / 256, blk, 0, stream>>>(out_w, wob);

    // fused embedding + entropy + LN1(layer 0): writes h and gb
    embed_ln_kernel<<<MM / 4, blk, 0, stream>>>(x, emb, ent_w, ent_b,
                                                ln1_s, ln1_b, h, gb);

    for (int layer = 0; layer < NLAYER; layer++) {
        const unsigned short* qw = wq + (size_t)layer * 3 * DD * DD;
        const unsigned short* aw = wa + (size_t)layer * DD * DD;
        const unsigned short* f1 = w1 + (size_t)layer * 4 * DD * DD;
        const unsigned short* f2 = w2 + (size_t)layer * DD * 4 * DD;
        const float* qb  = qkv_b + (size_t)layer * 3 * DD;
        const float* ab  = ao_b  + (size_t)layer * DD;
        const float* l1s = ln1_s + (size_t)layer * DD;
        const float* l1b = ln1_b + (size_t)layer * DD;
        const float* l2s = ln2_s + (size_t)layer * DD;
        const float* l2b = ln2_b + (size_t)layer * DD;
        const float* f1b = ff1_b + (size_t)layer * 4 * DD;
        const float* f2b = ff2_b + (size_t)layer * DD;

        // LN1 (layer 0 fused into embed_ln_kernel)
        if (layer > 0)
            ln_kernel<<<MM / 4, blk, 0, stream>>>(h, l1s, l1b, gb);

        // qkv = gb @ qw^T + qb -> bb (bf16) [MM,1536]
        {
            dim3 grid((3 * DD) / 128, MM / 128);
            gemm_mfma<true, false, false, 1><<<grid, blk, 0, stream>>>(
                gb, qw, qb, nullptr, bb, nullptr, 3 * DD, DD);
        }

        // attention: bb -> ob (bf16)
        attn_mfma<<<512, 512, 0, stream>>>(bb, ob);

        // h = h + ob @ aw^T + ab  (f32 out)
        {
            dim3 grid(DD / 128, MM / 128);
            gemm_mfma<true, false, true, 0><<<grid, blk, 0, stream>>>(
                ob, aw, ab, h, h, nullptr, DD, DD);
        }

        // LN2: h -> gb
        ln_kernel<<<MM / 4, blk, 0, stream>>>(h, l2s, l2b, gb);

        // ffn1: bb = gelu(gb @ f1^T + f1b) (bf16) [MM,2048]
        {
            dim3 grid((4 * DD) / 128, MM / 128);
            gemm_mfma<true, true, false, 1><<<grid, blk, 0, stream>>>(
                gb, f1, f1b, nullptr, bb, nullptr, 4 * DD, DD);
        }

        // ffn2: h = h + bb @ f2^T + f2b  (f32; last layer also emits bf16 hb)
        {
            dim3 grid(DD / 128, MM / 128);
            if (layer == NLAYER - 1)
                gemm_mfma<true, false, true, 2><<<grid, blk, 0, stream>>>(
                    bb, f2, f2b, h, h, hb, DD, 4 * DD);
            else
                gemm_mfma<true, false, true, 0><<<grid, blk, 0, stream>>>(
                    bb, f2, f2b, h, h, nullptr, DD, 4 * DD);
        }
    }

    // logits = hb @ wob^T [MM, 258] via MFMA on padded weight
    {
        dim3 grid(VPAD / 128, MM / 128);
        gemm_mfma<false, false, false, 0><<<grid, blk, 0, stream>>>(
            hb, wob, nullptr, nullptr, out, nullptr, VV, DD);
    }
}